// Round 9
// baseline (491.088 us; speedup 1.0000x reference)
//
#include <hip/hip_runtime.h>
#include <hip/hip_bf16.h>

typedef __hip_bfloat16 bf16;
typedef __attribute__((ext_vector_type(8))) short bf16x8;
typedef __attribute__((ext_vector_type(4))) float f32x4;
typedef __attribute__((ext_vector_type(4))) _Float16 f16x4;
typedef unsigned int u32;

#define BB 8
#define SS 512
#define DD 512
#define NH 8
#define DHm 256
#define DFF 2048

__device__ __forceinline__ void gl_lds16(const void* g, void* l) {
  __builtin_amdgcn_global_load_lds((const __attribute__((address_space(1))) void*)g,
                                   (__attribute__((address_space(3))) void*)l, 16, 0, 0);
}

__device__ __forceinline__ bf16x8 cvt8(const float* p) {
  union { bf16x8 v; bf16 h[8]; } u;
  float4 f0 = *(const float4*)p, f1 = *(const float4*)(p + 4);
  u.h[0]=__float2bfloat16(f0.x); u.h[1]=__float2bfloat16(f0.y);
  u.h[2]=__float2bfloat16(f0.z); u.h[3]=__float2bfloat16(f0.w);
  u.h[4]=__float2bfloat16(f1.x); u.h[5]=__float2bfloat16(f1.y);
  u.h[6]=__float2bfloat16(f1.z); u.h[7]=__float2bfloat16(f1.w);
  return u.v;
}

// ================= bf16 MFMA GEMM, double-buffered BK=64 K-loop =================
// A (M,K) bf16 row-major; B (N,K) bf16 row-major (pre-transposed weights).
// 2-phase: STAGE(next buf, both 32-col halves) issued BEFORE compute(cur buf);
// one vmcnt(0)+s_barrier per 64-K-iter -> 8 MFMA (64^2) / 32 MFMA (128^2) per barrier.
// SMODE: 1=fp32, 2=bf16, 3=both, 0=none. BIASM: 0 none, 1 per-col (+z*sBias), 2 scalar bias[0]+bias[1].
// VTM: 0 none; 1 QKV packed (QKF via Cb2, VT via Cb); 2 = z==0: Cb2[ci]=v*cscale[col],
//      z==1: ALSO emit transposed tile to Cb3 (QnT) via LDS bounce (coalesced).
#define STAGE2(buf, k0)                                                    \
  {                                                                        \
    _Pragma("unroll")                                                      \
    for (int j = 0; j < BM / 64; j++) {                                    \
      gl_lds16(Ab + (long long)(srow + j * 64) * lda + (k0) + skc,         \
               (char*)As[buf][0] + wave * 1024 + j * 4096);                \
      gl_lds16(Ab + (long long)(srow + j * 64) * lda + (k0) + 32 + skc,    \
               (char*)As[buf][1] + wave * 1024 + j * 4096);                \
    }                                                                      \
    _Pragma("unroll")                                                      \
    for (int j = 0; j < BN / 64; j++) {                                    \
      gl_lds16(Bb + (long long)(srow + j * 64) * ldb + (k0) + skc,         \
               (char*)Bs[buf][0] + wave * 1024 + j * 4096);                \
      gl_lds16(Bb + (long long)(srow + j * 64) * ldb + (k0) + 32 + skc,    \
               (char*)Bs[buf][1] + wave * 1024 + j * 4096);                \
    }                                                                      \
  }

template<int BM, int BN, int SMODE, int BIASM, int ACT, int VTM>
__global__ __launch_bounds__(256)
void gemm2(const bf16* __restrict__ A, const bf16* __restrict__ B,
           const float* __restrict__ bias, float* __restrict__ Cf,
           bf16* __restrict__ Cb, int K, int lda, int ldb, int ldc,
           long long sA, long long sB, long long sC, int sBias,
           bf16* __restrict__ Cb2, const float* __restrict__ cscale,
           bf16* __restrict__ Cb3)
{
  __shared__ bf16 As[2][2][BM * 32];
  __shared__ bf16 Bs[2][2][BN * 32];
  const int t = threadIdx.x, lane = t & 63, wave = t >> 6;
  const int l15 = lane & 15, quad = lane >> 4;
  constexpr int WMT = BM / 32, WNT = BN / 32;    // 16-tiles per wave in m/n
  const int wm = (wave & 1) * (BM / 2), wn = (wave >> 1) * (BN / 2);
  const int row0 = blockIdx.y * BM, col0 = blockIdx.x * BN;
  const bf16* Ab = A + (long long)blockIdx.z * sA + (long long)row0 * lda;
  const bf16* Bb = B + (long long)blockIdx.z * sB + (long long)col0 * ldb;
  const int srow = wave * 16 + (lane >> 2), skc = (lane & 3) << 3;

  f32x4 acc[WMT][WNT] = {};

  STAGE2(0, 0)
  asm volatile("s_waitcnt vmcnt(0)" ::: "memory");
  __builtin_amdgcn_s_barrier();

  int cur = 0;
  for (int k0 = 0; k0 < K; k0 += 64) {
    if (k0 + 64 < K) STAGE2(cur ^ 1, k0 + 64)
#pragma unroll
    for (int p = 0; p < 2; p++) {
      bf16x8 af[WMT], bfr[WNT];
#pragma unroll
      for (int i = 0; i < WMT; i++) af[i]  = *(const bf16x8*)&As[cur][p][(wm + i * 16 + l15) * 32 + quad * 8];
#pragma unroll
      for (int j = 0; j < WNT; j++) bfr[j] = *(const bf16x8*)&Bs[cur][p][(wn + j * 16 + l15) * 32 + quad * 8];
#pragma unroll
      for (int i = 0; i < WMT; i++)
#pragma unroll
        for (int j = 0; j < WNT; j++)
          acc[i][j] = __builtin_amdgcn_mfma_f32_16x16x32_bf16(af[i], bfr[j], acc[i][j], 0, 0, 0);
    }
    // staged loads (issued at loop top) had the whole compute phase to land
    asm volatile("s_waitcnt vmcnt(0)" ::: "memory");
    __builtin_amdgcn_s_barrier();
    cur ^= 1;
  }

  float sb = 0.f;
  if (BIASM == 2) sb = bias[0] + bias[1];
  bf16 (*tl)[65] = (bf16(*)[65])As;   // epilogue transpose scratch (VTM==2, z==1)
#pragma unroll
  for (int i = 0; i < WMT; i++)
#pragma unroll
    for (int j = 0; j < WNT; j++) {
      int col = col0 + wn + j * 16 + l15;
      float bv = (BIASM == 1) ? bias[(long long)blockIdx.z * sBias + col] : sb;
      float vv[4];
#pragma unroll
      for (int r = 0; r < 4; r++) {
        float v = acc[i][j][r] + bv;
        if (ACT == 1) v = fmaxf(v, 0.f);
        if (ACT == 2) v = 0.5f * v * (1.f + erff(v * 0.70710678118654752f));
        vv[r] = v;
      }
      const int rowb = row0 + wm + i * 16 + (quad << 2);
      if (VTM == 1) {
        const int bidx = rowb >> 9, kpos = rowb & 511;
        const long long zz8 = (long long)blockIdx.z * 8 + bidx;
        if (col < 512) {
          // QKF packed: [zz8][h][part(0=Q,1=K)][kpos][dep32]
          const int part = col >> 8, hh = (col >> 5) & 7, dep = col & 31;
          bf16* dst = Cb2 + (((zz8 * 8 + hh) * 2 + part) * 512 + (long long)kpos) * 32 + dep;
#pragma unroll
          for (int r = 0; r < 4; r++) dst[r * 32] = __float2bfloat16(vv[r]);
        } else {
          // VT packed: [zz8][h][kpos>>3][dep][kpos&7]
          const int hh = (col - 512) >> 5, dep = (col - 512) & 31;
          long long vo = ((zz8 * 8 + hh) * 64 + (kpos >> 3)) * 32 + dep;
          bf16 h0 = __float2bfloat16(vv[0]), h1 = __float2bfloat16(vv[1]);
          bf16 h2 = __float2bfloat16(vv[2]), h3 = __float2bfloat16(vv[3]);
          short4 pk;
          pk.x = *(short*)&h0; pk.y = *(short*)&h1; pk.z = *(short*)&h2; pk.w = *(short*)&h3;
          *(short4*)(Cb + vo * 8 + (kpos & 7)) = pk;
        }
      } else {
#pragma unroll
        for (int r = 0; r < 4; r++) {
          long long ci = (long long)blockIdx.z * sC + (long long)(rowb + r) * ldc + col;
          bf16 hb = __float2bfloat16(vv[r]);
          if (SMODE & 1) Cf[ci] = vv[r];
          if (SMODE & 2) Cb[ci] = hb;
          if (VTM == 2) {
            if (blockIdx.z == 0) Cb2[ci] = __float2bfloat16(vv[r] * cscale[col]);
            else tl[wm + i * 16 + (quad << 2) + r][wn + j * 16 + l15] = hb;
          }
        }
      }
    }

  // ---- VTM==2, z==1: emit transposed tile (QnT[c][r] = Qn[r][c]) coalesced ----
  if (VTM == 2 && blockIdx.z == 1) {
    __syncthreads();
    const int o_r = t >> 2;                 // output row within tile = original col
    const int jb = (t & 3) * 16;            // 16 source rows handled by this thread
    const int bidx = row0 >> 9;             // batch (tiles never cross 512-row bound)
    bf16* dst = Cb3 + (long long)bidx * 262144 + (long long)(col0 + o_r) * 512 + (row0 & 511) + jb;
    union { bf16x8 v; bf16 h[8]; } u0, u1;
#pragma unroll
    for (int j = 0; j < 8; j++) { u0.h[j] = tl[jb + j][o_r]; u1.h[j] = tl[jb + 8 + j][o_r]; }
    *(bf16x8*)dst = u0.v;
    *(bf16x8*)(dst + 8) = u1.v;
  }
}

// ================= fused MFMA attention, one pass (unchanged from r8) =================
__global__ __launch_bounds__(256, 2)
void attn_fused(const bf16* __restrict__ QKF, const bf16* __restrict__ VT,
                const int* __restrict__ mask, const _Float16* __restrict__ EP,
                float* __restrict__ awl, float* __restrict__ awg,
                bf16* __restrict__ ctx1, bf16* __restrict__ ctx2)
{
  const int qt = blockIdx.x, h = blockIdx.y, zz = blockIdx.z;
  const int b = zz & 7, branch = zz >> 3;
  float* __restrict__ aw = branch ? awg : awl;
  bf16* __restrict__ ctx = branch ? ctx2 : ctx1;

  const int t = threadIdx.x, lane = t & 63, wave = t >> 6;
  const int l15 = lane & 15, quad = lane >> 4;
  __shared__ bf16x8 Vt[64][32];                 // 32 KB
  alignas(16) __shared__ bf16 Pl[4][2048];      // 16 KB per-wave swizzled e chunk
  __shared__ float mvalf[512];                  // 2 KB

  // ---- stage V via async copy from pre-transposed VT ----
  const bf16* VTs = VT + ((long long)zz * 8 + h) * 16384;
#pragma unroll
  for (int j = 0; j < 8; j++)
    gl_lds16(VTs + (long long)t * 8 + j * 2048, (char*)Vt + wave * 1024 + j * 4096);

  { int2 m2 = *(const int2*)(mask + b * SS + t * 2);
    mvalf[t * 2]     = (float)m2.x * -1e9f;
    mvalf[t * 2 + 1] = (float)m2.y * -1e9f; }

  const int q0 = qt * 64 + wave * 16;
  const bf16* Qbase = QKF + ((long long)zz * 8 + h) * 2 * 16384;
  const bf16* Kbase = Qbase + 16384;
  bf16x8 qfrag = *(const bf16x8*)(Qbase + (long long)(q0 + l15) * 32 + quad * 8);
  __syncthreads();

  const float scale_inv = 0.17677669529663688f;
  const f16x4* Ep = (const f16x4*)EP + (((long long)zz * 8 + qt) * 4 + wave) * 2048;

  u32 eh[64];
  float rsum[4] = {0.f, 0.f, 0.f, 0.f};
  f32x4 oacc[2] = {};
  short* Pw = (short*)Pl[wave];
  const int rkey = ((l15 >> 2) ^ l15) & 3;

#pragma unroll
  for (int c = 0; c < 4; c++) {
#pragma unroll
    for (int kcl = 0; kcl < 8; kcl++) {
      const int kc = c * 8 + kcl;
      const int kpos = kc * 16 + l15;
      bf16x8 kfrag = *(const bf16x8*)(Kbase + (long long)kpos * 32 + quad * 8);
      f16x4 e4 = Ep[kc * 64 + lane];
      f32x4 a = __builtin_amdgcn_mfma_f32_16x16x32_bf16(qfrag, kfrag, f32x4{0.f,0.f,0.f,0.f}, 0, 0, 0);
      float mv = (branch == 0) ? 0.f : mvalf[kpos];
      u32 p01 = 0, p23 = 0;
#pragma unroll
      for (int r = 0; r < 4; r++) {
        float s = (branch == 0) ? fmaf(a[r], scale_inv, (float)e4[r])
                                : fmaf(fmaxf(a[r], 0.f), (float)e4[r], mv);
        float e = __expf(s);
        rsum[r] += e;
        u32 xb = __float_as_uint(e);
        u32 b16 = (xb + 0x7FFFu + ((xb >> 16) & 1u)) >> 16;   // RNE bf16, int-only
        if (r == 0)      p01 = b16;
        else if (r == 1) p01 |= b16 << 16;
        else if (r == 2) p23 = b16;
        else             p23 |= b16 << 16;
        const int key = (quad ^ r) & 3;          // ((row>>2)^row)&3 for row=quad*4+r
        const int off = (quad * 4 + r) * 256 + (((kcl * 16 + l15) * 2) ^ (key << 5));
        *(short*)((char*)Pw + off) = (short)b16;
      }
      eh[kc * 2]     = p01;
      eh[kc * 2 + 1] = p23;
    }
    // ---- PV on this chunk (unnormalized e) ----
    __builtin_amdgcn_s_setprio(1);
#pragma unroll
    for (int k2 = 0; k2 < 4; k2++) {
      const int off = l15 * 256 + ((k2 * 64 + quad * 16) ^ (rkey << 5));
      bf16x8 afr = *(const bf16x8*)((const char*)Pw + off);
      const int blk = (c * 4 + k2) * 4 + quad;
      oacc[0] = __builtin_amdgcn_mfma_f32_16x16x32_bf16(afr, Vt[blk][l15],      oacc[0], 0, 0, 0);
      oacc[1] = __builtin_amdgcn_mfma_f32_16x16x32_bf16(afr, Vt[blk][16 + l15], oacc[1], 0, 0, 0);
    }
    __builtin_amdgcn_s_setprio(0);
  }

  // ---- row sums -> 1/sum ----
  float rsi[4];
#pragma unroll
  for (int r = 0; r < 4; r++) {
    float v = rsum[r];
    v += __shfl_xor(v, 1, 16);
    v += __shfl_xor(v, 2, 16);
    v += __shfl_xor(v, 4, 16);
    v += __shfl_xor(v, 8, 16);
    rsi[r] = 1.f / v;
  }

  // ---- ctx = (e.V) * rsi ----
#pragma unroll
  for (int n = 0; n < 2; n++)
#pragma unroll
    for (int r = 0; r < 4; r++) {
      int q = q0 + quad * 4 + r;
      ctx[(long long)(b * SS + q) * DHm + h * 32 + n * 16 + l15] =
          __float2bfloat16(oacc[n][r] * rsi[r]);
    }

  // ---- aw = unpack(e) * rsi (plain cached stores) ----
  float* awp = aw + (((long long)(b * NH + h) * SS + q0)) * SS;
#pragma unroll
  for (int kc = 0; kc < 32; kc++) {
    u32 p01 = eh[kc * 2], p23 = eh[kc * 2 + 1];
#pragma unroll
    for (int r = 0; r < 4; r++) {
      u32 bits = (r == 0) ? (p01 & 0xFFFFu) : (r == 1) ? (p01 >> 16)
               : (r == 2) ? (p23 & 0xFFFFu) : (p23 >> 16);
      float e = __uint_as_float(bits << 16);
      awp[(long long)(quad * 4 + r) * SS + kc * 16 + l15] = e * rsi[r];
    }
  }
}

// ================= pack_all + eprep merged =================
__device__ __forceinline__ void tr_tile(const float* __restrict__ src, bf16* __restrict__ dst,
                                        int K, int N, int tile) {
  __shared__ float tl[32][33];
  int tilesN = N >> 5;
  int tk = tile / tilesN, tn = tile % tilesN;
  int c = threadIdx.x & 31, r0 = threadIdx.x >> 5;
#pragma unroll
  for (int i = 0; i < 4; i++) {
    int r = r0 + i * 8;
    tl[r][c] = src[(long long)(tk * 32 + r) * N + tn * 32 + c];
  }
  __syncthreads();
#pragma unroll
  for (int i = 0; i < 4; i++) {
    int r = r0 + i * 8;
    dst[(long long)(tn * 32 + r) * K + tk * 32 + c] = __float2bfloat16(tl[c][r]);
  }
}

__global__ __launch_bounds__(256)
void pack_all(const float* wq1, const float* wk1, const float* wv1,
              const float* wq2, const float* wk2, const float* wv2,
              const float* wo1, const float* wo2,
              const float* vnet_w, const float* qnet_w,
              const float* ffn_w1, const float* ffn_w2,
              const float* bq1, const float* bk1, const float* bv1,
              const float* bq2, const float* bk2, const float* bv2,
              const float* bo1, const float* bo2,
              const float* vnet_b, const float* qnet_b,
              const float* h_mat,
              const float* x,
              const float* adjoin, const float* dist, const int* mask,
              bf16* WB1, bf16* WB2, bf16* woT1, bf16* woT2,
              bf16* vnetT, bf16* qnetT, bf16* f1T, bf16* f2T,
              float* BB1v, float* BB2v, float* BOv, float* VQb, float* HSv,
              bf16* xb, _Float16* EP)
{
  int blk = blockIdx.x;
  if (blk < 64)        { tr_tile(wq1, WB1,            256, 256, blk); return; }
  if (blk < 128)       { tr_tile(wk1, WB1 + 256*256,  256, 256, blk-64); return; }
  if (blk < 192)       { tr_tile(wv1, WB1 + 512*256,  256, 256, blk-128); return; }
  if (blk < 256)       { tr_tile(wq2, WB2,            256, 256, blk-192); return; }
  if (blk < 320)       { tr_tile(wk2, WB2 + 256*256,  256, 256, blk-256); return; }
  if (blk < 384)       { tr_tile(wv2, WB2 + 512*256,  256, 256, blk-320); return; }
  if (blk < 448)       { tr_tile(wo1, woT1,           256, 256, blk-384); return; }
  if (blk < 512)       { tr_tile(wo2, woT2,           256, 256, blk-448); return; }
  if (blk < 640)       { tr_tile(vnet_w, vnetT,       256, 512, blk-512); return; }
  if (blk < 768)       { tr_tile(qnet_w, qnetT,       256, 512, blk-640); return; }
  if (blk < 1792)      { tr_tile(ffn_w1, f1T,         512, 2048, blk-768); return; }
  if (blk < 2816)      { tr_tile(ffn_w2, f2T,         2048, 512, blk-1792); return; }
  if (blk < 3840) {
    long long i0 = (long long)(blk - 2816) * 2048 + threadIdx.x * 8;
    *(bf16x8*)(xb + i0) = cvt8(x + i0);
    return;
  }
  if (blk < 3846) {
    int b = blk - 3840; // 0..5
    const float* src = b==0?bq1 : b==1?bk1 : b==2?bv1 : b==3?bq2 : b==4?bk2 : bv2;
    float* dst = (b < 3 ? BB1v : BB2v) + (b % 3) * 256;
    dst[threadIdx.x] = src[threadIdx.x];
    return;
  }
  if (blk < 3848) {
    int b = blk - 3846; // 0..1
    BOv[b * 256 + threadIdx.x] = (b ? bo2 : bo1)[threadIdx.x];
    return;
  }
  if (blk < 3852) {
    int b = blk - 3848; // 0..3: [vnet_b lo, vnet_b hi, qnet_b lo, qnet_b hi]
    const float* src = (b < 2) ? vnet_b : qnet_b;
    VQb[b * 256 + threadIdx.x] = src[(b & 1) * 256 + threadIdx.x];
    return;
  }
  if (blk < 3853) {
    int t = threadIdx.x;
    HSv[t]       = h_mat[t]       + h_mat[512 + t];
    HSv[t + 256] = h_mat[256 + t] + h_mat[768 + t];
    return;
  }
  // ---- eprep blocks: reorder extra-bias into MFMA lane order (fp16) ----
  {
    const int e = blk - 3853;             // 0..511
    const int qt = e & 7, kt = (e >> 3) & 3, zz = e >> 5;
    const int b = zz & 7, branch = zz >> 3;
    const float* E = (branch ? dist : adjoin) + ((long long)b * SS + qt * 64) * SS + kt * 128;
    __shared__ float tile[64][129];
    const int t = threadIdx.x;
    const int r0 = t >> 5, c4 = (t & 31) * 4;
#pragma unroll
    for (int jj = 0; jj < 8; jj++) {
      int row = r0 + jj * 8;
      float4 f = *(const float4*)(E + (long long)row * SS + c4);
      tile[row][c4 + 0] = f.x; tile[row][c4 + 1] = f.y;
      tile[row][c4 + 2] = f.z; tile[row][c4 + 3] = f.w;
    }
    __syncthreads();
    const int lane = t & 63, wq = t >> 6, l15 = lane & 15, quad = lane >> 4;
    const float scale_inv = 0.17677669529663688f; // 1/sqrt(32)
    f16x4* out = (f16x4*)EP;
#pragma unroll
    for (int kcl = 0; kcl < 8; kcl++) {
      int kk = kcl * 16 + l15;
      f16x4 o;
      if (branch == 0) {
        float mv = (float)mask[b * SS + kt * 128 + kk] * -1e9f;
#pragma unroll
        for (int r = 0; r < 4; r++)
          o[r] = (_Float16)(tile[wq * 16 + quad * 4 + r][kk] + mv);
      } else {
#pragma unroll
        for (int r = 0; r < 4; r++) {
          float ev = tile[wq * 16 + quad * 4 + r][kk];
          o[r] = (_Float16)(3.7182818284590452f / (1.f + __expf(1.f - ev)) * scale_inv);
        }
      }
      out[((((long long)zz * 8 + qt) * 4 + wq) * 32 + (kt * 8 + kcl)) * 64 + lane] = o;
    }
  }
}

// ---------------- BN(eval) + gate + residual + LN1 (dual-store, wave-shuffle reduce) ----------------
__global__ __launch_bounds__(256)
void bn_gate_ln1_kernel(const float* __restrict__ x, const bf16* __restrict__ vbuf,
                        const float* __restrict__ T, const float* __restrict__ xl,
                        const float* __restrict__ xg,
                        const float* __restrict__ bng, const float* __restrict__ bnb,
                        const float* __restrict__ bnm, const float* __restrict__ bnv,
                        const float* __restrict__ lng, const float* __restrict__ lnb,
                        float* __restrict__ out1, bf16* __restrict__ out1b)
{
  const int row = blockIdx.x;
  const int t = threadIdx.x;
  const int lane = t & 63, wave = t >> 6;
  __shared__ float red[8];
  float val[2];
#pragma unroll
  for (int i = 0; i < 2; i++) {
    int c = t + i * 256;
    long long idx = (long long)row * DD + c;
    float lg = __bfloat162float(vbuf[idx]) * T[idx];
    float bn = (lg - bnm[c]) / sqrtf(bnv[c] + 1e-3f) * bng[c] + bnb[c];
    float gate = (c < DHm) ? xl[(long long)row * DHm + c] : xg[(long long)row * DHm + (c - DHm)];
    val[i] = x[idx] + bn * gate;
  }
  float s = val[0] + val[1];
#pragma unroll
  for (int o = 32; o > 0; o >>= 1) s += __shfl_xor(s, o);
  if (lane == 0) red[wave] = s;
  __syncthreads();
  float mu = (red[0] + red[1] + red[2] + red[3]) * (1.f / 512.f);
  float d0 = val[0] - mu, d1 = val[1] - mu;
  float vs = d0 * d0 + d1 * d1;
#pragma unroll
  for (int o = 32; o > 0; o >>= 1) vs += __shfl_xor(vs, o);
  if (lane == 0) red[4 + wave] = vs;
  __syncthreads();
  float inv = 1.f / sqrtf((red[4] + red[5] + red[6] + red[7]) * (1.f / 512.f) + 1e-6f);
  float o0 = d0 * inv * lng[t] + lnb[t];
  float o1 = d1 * inv * lng[t + 256] + lnb[t + 256];
  out1[(long long)row * DD + t] = o0;
  out1[(long long)row * DD + t + 256] = o1;
  out1b[(long long)row * DD + t] = __float2bfloat16(o0);
  out1b[(long long)row * DD + t + 256] = __float2bfloat16(o1);
}

// ---------------- residual + LN2 -> out (wave-shuffle reduce) ----------------
__global__ __launch_bounds__(256)
void ln2_kernel(const float* __restrict__ a, const float* __restrict__ b2,
                const float* __restrict__ g, const float* __restrict__ bta,
                float* __restrict__ out)
{
  const int row = blockIdx.x;
  const int t = threadIdx.x;
  const int lane = t & 63, wave = t >> 6;
  __shared__ float red[8];
  float v0 = a[(long long)row * DD + t]       + b2[(long long)row * DD + t];
  float v1 = a[(long long)row * DD + t + 256] + b2[(long long)row * DD + t + 256];
  float s = v0 + v1;
#pragma unroll
  for (int o = 32; o > 0; o >>= 1) s += __shfl_xor(s, o);
  if (lane == 0) red[wave] = s;
  __syncthreads();
  float mu = (red[0] + red[1] + red[2] + red[3]) * (1.f / 512.f);
  float d0 = v0 - mu, d1 = v1 - mu;
  float vs = d0 * d0 + d1 * d1;
#pragma unroll
  for (int o = 32; o > 0; o >>= 1) vs += __shfl_xor(vs, o);
  if (lane == 0) red[4 + wave] = vs;
  __syncthreads();
  float inv = 1.f / sqrtf((red[4] + red[5] + red[6] + red[7]) * (1.f / 512.f) + 1e-6f);
  out[(long long)row * DD + t]       = d0 * inv * g[t]       + bta[t];
  out[(long long)row * DD + t + 256] = d1 * inv * g[t + 256] + bta[t + 256];
}

extern "C" void kernel_launch(void* const* d_in, const int* in_sizes, int n_in,
                              void* d_out, int out_size, void* d_ws, size_t ws_size,
                              hipStream_t stream) {
  const float* x      = (const float*)d_in[0];
  const float* adjoin = (const float*)d_in[1];
  const float* dist   = (const float*)d_in[2];
  const float* wq1=(const float*)d_in[3],  *bq1=(const float*)d_in[4];
  const float* wk1=(const float*)d_in[5],  *bk1=(const float*)d_in[6];
  const float* wv1=(const float*)d_in[7],  *bv1=(const float*)d_in[8];
  const float* wo1=(const float*)d_in[9],  *bo1=(const float*)d_in[10];
  const float* wq2=(const float*)d_in[11], *bq2=(const float*)d_in[12];
  const float* wk2=(const float*)d_in[13], *bk2=(const float*)d_in[14];
  const float* wv2=(const float*)d_in[15], *bv2=(const float*)d_in[16];
  const float* wo2=(const float*)d_in[17], *bo2=(const float*)d_in[18];
  const float* vnet_w=(const float*)d_in[19], *vnet_b=(const float*)d_in[20];
  const float* qnet_w=(const float*)d_in[21], *qnet_b=(const float*)d_in[22];
  const float* h_mat=(const float*)d_in[23], *h_bias=(const float*)d_in[24];
  const float* bn_g=(const float*)d_in[25], *bn_b=(const float*)d_in[26];
  const float* bn_m=(const float*)d_in[27], *bn_v=(const float*)d_in[28];
  const float* ln1_g=(const float*)d_in[29], *ln1_b=(const float*)d_in[30];
  const float* ln2_g=(const float*)d_in[31], *ln2_b=(const float*)d_in[32];
  const float* ffn_w1=(const float*)d_in[33], *ffn_b1=(const float*)d_in[34];
  const float* ffn_w2=(const float*)d_in[35], *ffn_b2=(const float*)d_in[36];
  const int* mask = (const int*)d_in[37];

  // ---- workspace layout (bytes). Adjacent pairs relied upon for z-batched gemms.
  char* base = (char*)d_ws;
  size_t off = 0;
  auto alloc = [&](size_t bytes) { char* p = base + off; off += (bytes + 255) & ~(size_t)255; return p; };
  bf16*  xb    = (bf16*) alloc(4096LL*512*2);
  bf16*  WB1   = (bf16*) alloc(768*256*2);   // pair: WB2 follows
  bf16*  WB2   = (bf16*) alloc(768*256*2);
  float* BB1v  = (float*)alloc(768*4);       // pair: BB2v follows
  float* BB2v  = (float*)alloc(768*4);
  float* BOv   = (float*)alloc(512*4);       // [bo1|bo2]
  float* VQb   = (float*)alloc(1024*4);      // [vnet_b|qnet_b]
  float* HSv   = (float*)alloc(512*4);       // hmat[0,:]+hmat[1,:]
  bf16*  woT1  = (bf16*) alloc(256*256*2);   // pair: woT2 follows
  bf16*  woT2  = (bf16*) alloc(256*256*2);
  bf16*  vnetT = (bf16*) alloc(512*256*2);   // pair: qnetT follows
  bf16*  qnetT = (bf16*) alloc(512*256*2);
  bf16*  f1T   = (bf16*) alloc(2048*512*2);
  bf16*  f2T   = (bf16*) alloc(512*2048*2);
  bf16*  QKF   = (bf16*) alloc(16LL*8*2*512*32*2); // 8 MB packed Q|K fragments
  bf16*  VTb   = (bf16*) alloc(2LL*8*8*512*32*2);  // 4 MB blocked-transposed V
  _Float16* EP = (_Float16*)alloc(8388608);        // 8.4 MB lane-ordered extra bias (fp16)
  bf16*  CTX   = (bf16*) alloc(4096LL*256*2); // pair: CTX2 follows
  bf16*  CTX2  = (bf16*) alloc(4096LL*256*2);
  float* XL    = (float*)alloc(4096LL*256*4); // pair: XG follows
  float* XG    = (float*)alloc(4096LL*256*4);
  bf16*  XLb   = (bf16*) alloc(4096LL*256*2); // pair: XGb follows
  bf16*  XGb   = (bf16*) alloc(4096LL*256*2);
  bf16*  Vn    = (bf16*) alloc(4096LL*512*2); // pair: Qn follows
  bf16*  Qn    = (bf16*) alloc(4096LL*512*2);
  bf16*  QnT   = (bf16*) alloc(4096LL*512*2);
  bf16*  VH    = (bf16*) alloc(4096LL*512*2);
  bf16*  G     = (bf16*) alloc(8LL*512*512*2);
  float* T     = (float*)alloc(4096LL*512*4);
  float* OUT1  = (float*)alloc(4096LL*512*4);
  bf16*  OUT1b = (bf16*) alloc(4096LL*512*2);
  bf16*  H     = (bf16*) alloc(4096LL*2048*2);
  float* FFNO  = (float*)alloc(4096LL*512*4);

  float* out2 = (float*)d_out;
  float* awl  = out2 + 2097152LL;
  float* awg  = awl + 16777216LL;

  const int MR = BB * SS; // 4096
  const long long GST = (long long)SS * SS;

  // ---- pack everything to bf16 + eprep (merged, one launch) ----
  pack_all<<<dim3(4365), 256, 0, stream>>>(
      wq1, wk1, wv1, wq2, wk2, wv2, wo1, wo2, vnet_w, qnet_w, ffn_w1, ffn_w2,
      bq1, bk1, bv1, bq2, bk2, bv2, bo1, bo2, vnet_b, qnet_b, h_mat, x,
      adjoin, dist, mask,
      WB1, WB2, woT1, woT2, vnetT, qnetT, f1T, f2T, BB1v, BB2v, BOv, VQb, HSv,
      xb, EP);

  // ---- QKV projections, both branches batched; epilogue writes packed QKF + VT ----
  gemm2<128,128,0,1,0,1><<<dim3(6, 32, 2), 256, 0, stream>>>(
      xb, WB1, BB1v, nullptr, VTb, 256, 512, 256, 768,
      256LL, 768LL*256, 0LL, 768, QKF, nullptr, nullptr);

  // ---- attention, both branches, one pass ----
  attn_fused<<<dim3(8, NH, 16), 256, 0, stream>>>(
      QKF, VTb, mask, EP, awl, awg, CTX, CTX2);

  // ---- output projections, batched over z ----
  gemm2<64,64,3,1,0,0><<<dim3(4, 64, 2), 256, 0, stream>>>(
      CTX, woT1, BOv, XL, XLb, 256, 256, 256, 256,
      4096LL*256, 256LL*256, 4096LL*256, 256, nullptr, nullptr, nullptr);

  // ---- BAN v_/q_ nets batched; z==0 also emits VH=v_*hsum; z==1 also emits QnT ----
  gemm2<64,64,2,1,1,2><<<dim3(8, 64, 2), 256, 0, stream>>>(
      XLb, vnetT, VQb, nullptr, Vn, 256, 256, 256, 512,
      4096LL*256, 512LL*256, 4096LL*512, 512, VH, HSv, QnT);

  gemm2<64,64,2,2,0,0><<<dim3(8, 8, BB), 256, 0, stream>>>(
      VH, Qn, h_bias, nullptr, G, 512, 512, 512, 512, GST, GST, GST, 0, nullptr, nullptr, nullptr);
  gemm2<64,64,1,0,0,0><<<dim3(8, 8, BB), 256, 0, stream>>>(
      G, QnT, nullptr, T, nullptr, 512, 512, 512, 512, GST, GST, GST, 0, nullptr, nullptr, nullptr);

  // ---- BN + gate + residual + LN1 ----
  bn_gate_ln1_kernel<<<dim3(MR), 256, 0, stream>>>(
      x, Vn, T, XL, XG, bn_g, bn_b, bn_m, bn_v, ln1_g, ln1_b, OUT1, OUT1b);

  // ---- FFN ----
  gemm2<128,128,2,1,2,0><<<dim3(16, 32, 1), 256, 0, stream>>>(
      OUT1b, f1T, ffn_b1, nullptr, H, 512, 512, 512, 2048, 0, 0, 0, 0, nullptr, nullptr, nullptr);
  gemm2<64,64,1,1,0,0><<<dim3(8, 64, 1), 256, 0, stream>>>(
      H, f2T, ffn_b2, FFNO, nullptr, 2048, 2048, 2048, 512, 0, 0, 0, 0, nullptr, nullptr, nullptr);

  // ---- residual + LN2 -> out ----
  ln2_kernel<<<dim3(MR), 256, 0, stream>>>(OUT1, FFNO, ln2_g, ln2_b, out2);
}

// Round 10
// 443.986 us; speedup vs baseline: 1.1061x; 1.1061x over previous
//
#include <hip/hip_runtime.h>
#include <hip/hip_bf16.h>

typedef __hip_bfloat16 bf16;
typedef __attribute__((ext_vector_type(8))) short bf16x8;
typedef __attribute__((ext_vector_type(4))) float f32x4;
typedef __attribute__((ext_vector_type(4))) _Float16 f16x4;
typedef unsigned int u32;

#define BB 8
#define SS 512
#define DD 512
#define NH 8
#define DHm 256
#define DFF 2048

__device__ __forceinline__ void gl_lds16(const void* g, void* l) {
  __builtin_amdgcn_global_load_lds((const __attribute__((address_space(1))) void*)g,
                                   (__attribute__((address_space(3))) void*)l, 16, 0, 0);
}

__device__ __forceinline__ bf16x8 cvt8(const float* p) {
  union { bf16x8 v; bf16 h[8]; } u;
  float4 f0 = *(const float4*)p, f1 = *(const float4*)(p + 4);
  u.h[0]=__float2bfloat16(f0.x); u.h[1]=__float2bfloat16(f0.y);
  u.h[2]=__float2bfloat16(f0.z); u.h[3]=__float2bfloat16(f0.w);
  u.h[4]=__float2bfloat16(f1.x); u.h[5]=__float2bfloat16(f1.y);
  u.h[6]=__float2bfloat16(f1.z); u.h[7]=__float2bfloat16(f1.w);
  return u.v;
}

// ================= bf16 MFMA GEMM, double-buffered BK=32 2-phase K-loop =================
// (r8 structure — measured best. r9's BK=64 cut blocks/CU 8->5 (64^2) and 5->2 (128^2);
// occupancy/TLP was the critical resource, not barrier count: regressed +47us. Reverted.)
// A (M,K) bf16 row-major; B (N,K) bf16 row-major (pre-transposed weights).
// STAGE(next buf) issued BEFORE compute(cur buf); one vmcnt(0)+s_barrier per K-iter.
// SMODE: 1=fp32, 2=bf16, 3=both, 0=none. BIASM: 0 none, 1 per-col (+z*sBias), 2 scalar bias[0]+bias[1].
// VTM: 0 none; 1 QKV packed (QKF via Cb2, VT via Cb); 2 = z==0: Cb2[ci]=v*cscale[col],
//      z==1: emit transposed tile to Cb3 (QnT) via dedicated LDS scratch (coalesced).
#define STAGE_G(buf, k0)                                                   \
  {                                                                        \
    _Pragma("unroll")                                                      \
    for (int j = 0; j < BM / 64; j++)                                      \
      gl_lds16(Ab + (long long)(srow + j * 64) * lda + (k0) + skc,         \
               (char*)As[buf] + wave * 1024 + j * 4096);                   \
    _Pragma("unroll")                                                      \
    for (int j = 0; j < BN / 64; j++)                                      \
      gl_lds16(Bb + (long long)(srow + j * 64) * ldb + (k0) + skc,         \
               (char*)Bs[buf] + wave * 1024 + j * 4096);                   \
  }

template<int BM, int BN, int SMODE, int BIASM, int ACT, int VTM>
__global__ __launch_bounds__(256)
void gemm2(const bf16* __restrict__ A, const bf16* __restrict__ B,
           const float* __restrict__ bias, float* __restrict__ Cf,
           bf16* __restrict__ Cb, int K, int lda, int ldb, int ldc,
           long long sA, long long sB, long long sC, int sBias,
           bf16* __restrict__ Cb2, const float* __restrict__ cscale,
           bf16* __restrict__ Cb3)
{
  __shared__ bf16 As[2][BM * 32];
  __shared__ bf16 Bs[2][BN * 32];
  __shared__ bf16 tls[(VTM == 2) ? 64 * 65 : 1];   // transpose scratch (vnet only)
  const int t = threadIdx.x, lane = t & 63, wave = t >> 6;
  const int l15 = lane & 15, quad = lane >> 4;
  constexpr int WMT = BM / 32, WNT = BN / 32;    // 16-tiles per wave in m/n
  const int wm = (wave & 1) * (BM / 2), wn = (wave >> 1) * (BN / 2);
  const int row0 = blockIdx.y * BM, col0 = blockIdx.x * BN;
  const bf16* Ab = A + (long long)blockIdx.z * sA + (long long)row0 * lda;
  const bf16* Bb = B + (long long)blockIdx.z * sB + (long long)col0 * ldb;
  const int srow = wave * 16 + (lane >> 2), skc = (lane & 3) << 3;

  f32x4 acc[WMT][WNT] = {};

  STAGE_G(0, 0)
  asm volatile("s_waitcnt vmcnt(0)" ::: "memory");
  __builtin_amdgcn_s_barrier();

  int cur = 0;
  for (int k0 = 0; k0 < K; k0 += 32) {
    if (k0 + 32 < K) STAGE_G(cur ^ 1, k0 + 32)
    bf16x8 af[WMT], bfr[WNT];
#pragma unroll
    for (int i = 0; i < WMT; i++) af[i]  = *(const bf16x8*)&As[cur][(wm + i * 16 + l15) * 32 + quad * 8];
#pragma unroll
    for (int j = 0; j < WNT; j++) bfr[j] = *(const bf16x8*)&Bs[cur][(wn + j * 16 + l15) * 32 + quad * 8];
#pragma unroll
    for (int i = 0; i < WMT; i++)
#pragma unroll
      for (int j = 0; j < WNT; j++)
        acc[i][j] = __builtin_amdgcn_mfma_f32_16x16x32_bf16(af[i], bfr[j], acc[i][j], 0, 0, 0);
    // staged loads (issued at loop top) had the whole compute phase to land
    asm volatile("s_waitcnt vmcnt(0)" ::: "memory");
    __builtin_amdgcn_s_barrier();
    cur ^= 1;
  }

  float sb = 0.f;
  if (BIASM == 2) sb = bias[0] + bias[1];
  bf16 (*tl)[65] = (bf16(*)[65])tls;
#pragma unroll
  for (int i = 0; i < WMT; i++)
#pragma unroll
    for (int j = 0; j < WNT; j++) {
      int col = col0 + wn + j * 16 + l15;
      float bv = (BIASM == 1) ? bias[(long long)blockIdx.z * sBias + col] : sb;
      float vv[4];
#pragma unroll
      for (int r = 0; r < 4; r++) {
        float v = acc[i][j][r] + bv;
        if (ACT == 1) v = fmaxf(v, 0.f);
        if (ACT == 2) v = 0.5f * v * (1.f + erff(v * 0.70710678118654752f));
        vv[r] = v;
      }
      const int rowb = row0 + wm + i * 16 + (quad << 2);
      if (VTM == 1) {
        const int bidx = rowb >> 9, kpos = rowb & 511;
        const long long zz8 = (long long)blockIdx.z * 8 + bidx;
        if (col < 512) {
          // QKF packed: [zz8][h][part(0=Q,1=K)][kpos][dep32]
          const int part = col >> 8, hh = (col >> 5) & 7, dep = col & 31;
          bf16* dst = Cb2 + (((zz8 * 8 + hh) * 2 + part) * 512 + (long long)kpos) * 32 + dep;
#pragma unroll
          for (int r = 0; r < 4; r++) dst[r * 32] = __float2bfloat16(vv[r]);
        } else {
          // VT packed: [zz8][h][kpos>>3][dep][kpos&7]
          const int hh = (col - 512) >> 5, dep = (col - 512) & 31;
          long long vo = ((zz8 * 8 + hh) * 64 + (kpos >> 3)) * 32 + dep;
          bf16 h0 = __float2bfloat16(vv[0]), h1 = __float2bfloat16(vv[1]);
          bf16 h2 = __float2bfloat16(vv[2]), h3 = __float2bfloat16(vv[3]);
          short4 pk;
          pk.x = *(short*)&h0; pk.y = *(short*)&h1; pk.z = *(short*)&h2; pk.w = *(short*)&h3;
          *(short4*)(Cb + vo * 8 + (kpos & 7)) = pk;
        }
      } else {
#pragma unroll
        for (int r = 0; r < 4; r++) {
          long long ci = (long long)blockIdx.z * sC + (long long)(rowb + r) * ldc + col;
          bf16 hb = __float2bfloat16(vv[r]);
          if (SMODE & 1) Cf[ci] = vv[r];
          if (SMODE & 2) Cb[ci] = hb;
          if (VTM == 2) {
            if (blockIdx.z == 0) Cb2[ci] = __float2bfloat16(vv[r] * cscale[col]);
            else tl[wm + i * 16 + (quad << 2) + r][wn + j * 16 + l15] = hb;
          }
        }
      }
    }

  // ---- VTM==2, z==1: emit transposed tile (QnT[c][r] = Qn[r][c]) coalesced ----
  if (VTM == 2 && blockIdx.z == 1) {
    __syncthreads();
    const int o_r = t >> 2;                 // output row within tile = original col
    const int jb = (t & 3) * 16;            // 16 source rows handled by this thread
    const int bidx = row0 >> 9;             // batch (tiles never cross 512-row bound)
    bf16* dst = Cb3 + (long long)bidx * 262144 + (long long)(col0 + o_r) * 512 + (row0 & 511) + jb;
    union { bf16x8 v; bf16 h[8]; } u0, u1;
#pragma unroll
    for (int j = 0; j < 8; j++) { u0.h[j] = tl[jb + j][o_r]; u1.h[j] = tl[jb + 8 + j][o_r]; }
    *(bf16x8*)dst = u0.v;
    *(bf16x8*)(dst + 8) = u1.v;
  }
}

// ================= fused MFMA attention, one pass (unchanged from r7/r8) =================
__global__ __launch_bounds__(256, 2)
void attn_fused(const bf16* __restrict__ QKF, const bf16* __restrict__ VT,
                const int* __restrict__ mask, const _Float16* __restrict__ EP,
                float* __restrict__ awl, float* __restrict__ awg,
                bf16* __restrict__ ctx1, bf16* __restrict__ ctx2)
{
  const int qt = blockIdx.x, h = blockIdx.y, zz = blockIdx.z;
  const int b = zz & 7, branch = zz >> 3;
  float* __restrict__ aw = branch ? awg : awl;
  bf16* __restrict__ ctx = branch ? ctx2 : ctx1;

  const int t = threadIdx.x, lane = t & 63, wave = t >> 6;
  const int l15 = lane & 15, quad = lane >> 4;
  __shared__ bf16x8 Vt[64][32];                 // 32 KB
  alignas(16) __shared__ bf16 Pl[4][2048];      // 16 KB per-wave swizzled e chunk
  __shared__ float mvalf[512];                  // 2 KB

  // ---- stage V via async copy from pre-transposed VT ----
  const bf16* VTs = VT + ((long long)zz * 8 + h) * 16384;
#pragma unroll
  for (int j = 0; j < 8; j++)
    gl_lds16(VTs + (long long)t * 8 + j * 2048, (char*)Vt + wave * 1024 + j * 4096);

  { int2 m2 = *(const int2*)(mask + b * SS + t * 2);
    mvalf[t * 2]     = (float)m2.x * -1e9f;
    mvalf[t * 2 + 1] = (float)m2.y * -1e9f; }

  const int q0 = qt * 64 + wave * 16;
  const bf16* Qbase = QKF + ((long long)zz * 8 + h) * 2 * 16384;
  const bf16* Kbase = Qbase + 16384;
  bf16x8 qfrag = *(const bf16x8*)(Qbase + (long long)(q0 + l15) * 32 + quad * 8);
  __syncthreads();

  const float scale_inv = 0.17677669529663688f;
  const f16x4* Ep = (const f16x4*)EP + (((long long)zz * 8 + qt) * 4 + wave) * 2048;

  u32 eh[64];
  float rsum[4] = {0.f, 0.f, 0.f, 0.f};
  f32x4 oacc[2] = {};
  short* Pw = (short*)Pl[wave];
  const int rkey = ((l15 >> 2) ^ l15) & 3;

#pragma unroll
  for (int c = 0; c < 4; c++) {
#pragma unroll
    for (int kcl = 0; kcl < 8; kcl++) {
      const int kc = c * 8 + kcl;
      const int kpos = kc * 16 + l15;
      bf16x8 kfrag = *(const bf16x8*)(Kbase + (long long)kpos * 32 + quad * 8);
      f16x4 e4 = Ep[kc * 64 + lane];
      f32x4 a = __builtin_amdgcn_mfma_f32_16x16x32_bf16(qfrag, kfrag, f32x4{0.f,0.f,0.f,0.f}, 0, 0, 0);
      float mv = (branch == 0) ? 0.f : mvalf[kpos];
      u32 p01 = 0, p23 = 0;
#pragma unroll
      for (int r = 0; r < 4; r++) {
        float s = (branch == 0) ? fmaf(a[r], scale_inv, (float)e4[r])
                                : fmaf(fmaxf(a[r], 0.f), (float)e4[r], mv);
        float e = __expf(s);
        rsum[r] += e;
        u32 xb = __float_as_uint(e);
        u32 b16 = (xb + 0x7FFFu + ((xb >> 16) & 1u)) >> 16;   // RNE bf16, int-only
        if (r == 0)      p01 = b16;
        else if (r == 1) p01 |= b16 << 16;
        else if (r == 2) p23 = b16;
        else             p23 |= b16 << 16;
        const int key = (quad ^ r) & 3;          // ((row>>2)^row)&3 for row=quad*4+r
        const int off = (quad * 4 + r) * 256 + (((kcl * 16 + l15) * 2) ^ (key << 5));
        *(short*)((char*)Pw + off) = (short)b16;
      }
      eh[kc * 2]     = p01;
      eh[kc * 2 + 1] = p23;
    }
    // ---- PV on this chunk (unnormalized e) ----
    __builtin_amdgcn_s_setprio(1);
#pragma unroll
    for (int k2 = 0; k2 < 4; k2++) {
      const int off = l15 * 256 + ((k2 * 64 + quad * 16) ^ (rkey << 5));
      bf16x8 afr = *(const bf16x8*)((const char*)Pw + off);
      const int blk = (c * 4 + k2) * 4 + quad;
      oacc[0] = __builtin_amdgcn_mfma_f32_16x16x32_bf16(afr, Vt[blk][l15],      oacc[0], 0, 0, 0);
      oacc[1] = __builtin_amdgcn_mfma_f32_16x16x32_bf16(afr, Vt[blk][16 + l15], oacc[1], 0, 0, 0);
    }
    __builtin_amdgcn_s_setprio(0);
  }

  // ---- row sums -> 1/sum ----
  float rsi[4];
#pragma unroll
  for (int r = 0; r < 4; r++) {
    float v = rsum[r];
    v += __shfl_xor(v, 1, 16);
    v += __shfl_xor(v, 2, 16);
    v += __shfl_xor(v, 4, 16);
    v += __shfl_xor(v, 8, 16);
    rsi[r] = 1.f / v;
  }

  // ---- ctx = (e.V) * rsi ----
#pragma unroll
  for (int n = 0; n < 2; n++)
#pragma unroll
    for (int r = 0; r < 4; r++) {
      int q = q0 + quad * 4 + r;
      ctx[(long long)(b * SS + q) * DHm + h * 32 + n * 16 + l15] =
          __float2bfloat16(oacc[n][r] * rsi[r]);
    }

  // ---- aw = unpack(e) * rsi (plain cached stores) ----
  float* awp = aw + (((long long)(b * NH + h) * SS + q0)) * SS;
#pragma unroll
  for (int kc = 0; kc < 32; kc++) {
    u32 p01 = eh[kc * 2], p23 = eh[kc * 2 + 1];
#pragma unroll
    for (int r = 0; r < 4; r++) {
      u32 bits = (r == 0) ? (p01 & 0xFFFFu) : (r == 1) ? (p01 >> 16)
               : (r == 2) ? (p23 & 0xFFFFu) : (p23 >> 16);
      float e = __uint_as_float(bits << 16);
      awp[(long long)(quad * 4 + r) * SS + kc * 16 + l15] = e * rsi[r];
    }
  }
}

// ================= pack_all + eprep merged =================
__device__ __forceinline__ void tr_tile(const float* __restrict__ src, bf16* __restrict__ dst,
                                        int K, int N, int tile) {
  __shared__ float tl[32][33];
  int tilesN = N >> 5;
  int tk = tile / tilesN, tn = tile % tilesN;
  int c = threadIdx.x & 31, r0 = threadIdx.x >> 5;
#pragma unroll
  for (int i = 0; i < 4; i++) {
    int r = r0 + i * 8;
    tl[r][c] = src[(long long)(tk * 32 + r) * N + tn * 32 + c];
  }
  __syncthreads();
#pragma unroll
  for (int i = 0; i < 4; i++) {
    int r = r0 + i * 8;
    dst[(long long)(tn * 32 + r) * K + tk * 32 + c] = __float2bfloat16(tl[c][r]);
  }
}

__global__ __launch_bounds__(256)
void pack_all(const float* wq1, const float* wk1, const float* wv1,
              const float* wq2, const float* wk2, const float* wv2,
              const float* wo1, const float* wo2,
              const float* vnet_w, const float* qnet_w,
              const float* ffn_w1, const float* ffn_w2,
              const float* bq1, const float* bk1, const float* bv1,
              const float* bq2, const float* bk2, const float* bv2,
              const float* bo1, const float* bo2,
              const float* vnet_b, const float* qnet_b,
              const float* h_mat,
              const float* x,
              const float* adjoin, const float* dist, const int* mask,
              bf16* WB1, bf16* WB2, bf16* woT1, bf16* woT2,
              bf16* vnetT, bf16* qnetT, bf16* f1T, bf16* f2T,
              float* BB1v, float* BB2v, float* BOv, float* VQb, float* HSv,
              bf16* xb, _Float16* EP)
{
  int blk = blockIdx.x;
  if (blk < 64)        { tr_tile(wq1, WB1,            256, 256, blk); return; }
  if (blk < 128)       { tr_tile(wk1, WB1 + 256*256,  256, 256, blk-64); return; }
  if (blk < 192)       { tr_tile(wv1, WB1 + 512*256,  256, 256, blk-128); return; }
  if (blk < 256)       { tr_tile(wq2, WB2,            256, 256, blk-192); return; }
  if (blk < 320)       { tr_tile(wk2, WB2 + 256*256,  256, 256, blk-256); return; }
  if (blk < 384)       { tr_tile(wv2, WB2 + 512*256,  256, 256, blk-320); return; }
  if (blk < 448)       { tr_tile(wo1, woT1,           256, 256, blk-384); return; }
  if (blk < 512)       { tr_tile(wo2, woT2,           256, 256, blk-448); return; }
  if (blk < 640)       { tr_tile(vnet_w, vnetT,       256, 512, blk-512); return; }
  if (blk < 768)       { tr_tile(qnet_w, qnetT,       256, 512, blk-640); return; }
  if (blk < 1792)      { tr_tile(ffn_w1, f1T,         512, 2048, blk-768); return; }
  if (blk < 2816)      { tr_tile(ffn_w2, f2T,         2048, 512, blk-1792); return; }
  if (blk < 3840) {
    long long i0 = (long long)(blk - 2816) * 2048 + threadIdx.x * 8;
    *(bf16x8*)(xb + i0) = cvt8(x + i0);
    return;
  }
  if (blk < 3846) {
    int b = blk - 3840; // 0..5
    const float* src = b==0?bq1 : b==1?bk1 : b==2?bv1 : b==3?bq2 : b==4?bk2 : bv2;
    float* dst = (b < 3 ? BB1v : BB2v) + (b % 3) * 256;
    dst[threadIdx.x] = src[threadIdx.x];
    return;
  }
  if (blk < 3848) {
    int b = blk - 3846; // 0..1
    BOv[b * 256 + threadIdx.x] = (b ? bo2 : bo1)[threadIdx.x];
    return;
  }
  if (blk < 3852) {
    int b = blk - 3848; // 0..3: [vnet_b lo, vnet_b hi, qnet_b lo, qnet_b hi]
    const float* src = (b < 2) ? vnet_b : qnet_b;
    VQb[b * 256 + threadIdx.x] = src[(b & 1) * 256 + threadIdx.x];
    return;
  }
  if (blk < 3853) {
    int t = threadIdx.x;
    HSv[t]       = h_mat[t]       + h_mat[512 + t];
    HSv[t + 256] = h_mat[256 + t] + h_mat[768 + t];
    return;
  }
  // ---- eprep blocks: reorder extra-bias into MFMA lane order (fp16) ----
  {
    const int e = blk - 3853;             // 0..511
    const int qt = e & 7, kt = (e >> 3) & 3, zz = e >> 5;
    const int b = zz & 7, branch = zz >> 3;
    const float* E = (branch ? dist : adjoin) + ((long long)b * SS + qt * 64) * SS + kt * 128;
    __shared__ float tile[64][129];
    const int t = threadIdx.x;
    const int r0 = t >> 5, c4 = (t & 31) * 4;
#pragma unroll
    for (int jj = 0; jj < 8; jj++) {
      int row = r0 + jj * 8;
      float4 f = *(const float4*)(E + (long long)row * SS + c4);
      tile[row][c4 + 0] = f.x; tile[row][c4 + 1] = f.y;
      tile[row][c4 + 2] = f.z; tile[row][c4 + 3] = f.w;
    }
    __syncthreads();
    const int lane = t & 63, wq = t >> 6, l15 = lane & 15, quad = lane >> 4;
    const float scale_inv = 0.17677669529663688f; // 1/sqrt(32)
    f16x4* out = (f16x4*)EP;
#pragma unroll
    for (int kcl = 0; kcl < 8; kcl++) {
      int kk = kcl * 16 + l15;
      f16x4 o;
      if (branch == 0) {
        float mv = (float)mask[b * SS + kt * 128 + kk] * -1e9f;
#pragma unroll
        for (int r = 0; r < 4; r++)
          o[r] = (_Float16)(tile[wq * 16 + quad * 4 + r][kk] + mv);
      } else {
#pragma unroll
        for (int r = 0; r < 4; r++) {
          float ev = tile[wq * 16 + quad * 4 + r][kk];
          o[r] = (_Float16)(3.7182818284590452f / (1.f + __expf(1.f - ev)) * scale_inv);
        }
      }
      out[((((long long)zz * 8 + qt) * 4 + wq) * 32 + (kt * 8 + kcl)) * 64 + lane] = o;
    }
  }
}

// ---------------- BN(eval) + gate + residual + LN1 (dual-store, wave-shuffle reduce) ----------------
__global__ __launch_bounds__(256)
void bn_gate_ln1_kernel(const float* __restrict__ x, const bf16* __restrict__ vbuf,
                        const float* __restrict__ T, const float* __restrict__ xl,
                        const float* __restrict__ xg,
                        const float* __restrict__ bng, const float* __restrict__ bnb,
                        const float* __restrict__ bnm, const float* __restrict__ bnv,
                        const float* __restrict__ lng, const float* __restrict__ lnb,
                        float* __restrict__ out1, bf16* __restrict__ out1b)
{
  const int row = blockIdx.x;
  const int t = threadIdx.x;
  const int lane = t & 63, wave = t >> 6;
  __shared__ float red[8];
  float val[2];
#pragma unroll
  for (int i = 0; i < 2; i++) {
    int c = t + i * 256;
    long long idx = (long long)row * DD + c;
    float lg = __bfloat162float(vbuf[idx]) * T[idx];
    float bn = (lg - bnm[c]) / sqrtf(bnv[c] + 1e-3f) * bng[c] + bnb[c];
    float gate = (c < DHm) ? xl[(long long)row * DHm + c] : xg[(long long)row * DHm + (c - DHm)];
    val[i] = x[idx] + bn * gate;
  }
  float s = val[0] + val[1];
#pragma unroll
  for (int o = 32; o > 0; o >>= 1) s += __shfl_xor(s, o);
  if (lane == 0) red[wave] = s;
  __syncthreads();
  float mu = (red[0] + red[1] + red[2] + red[3]) * (1.f / 512.f);
  float d0 = val[0] - mu, d1 = val[1] - mu;
  float vs = d0 * d0 + d1 * d1;
#pragma unroll
  for (int o = 32; o > 0; o >>= 1) vs += __shfl_xor(vs, o);
  if (lane == 0) red[4 + wave] = vs;
  __syncthreads();
  float inv = 1.f / sqrtf((red[4] + red[5] + red[6] + red[7]) * (1.f / 512.f) + 1e-6f);
  float o0 = d0 * inv * lng[t] + lnb[t];
  float o1 = d1 * inv * lng[t + 256] + lnb[t + 256];
  out1[(long long)row * DD + t] = o0;
  out1[(long long)row * DD + t + 256] = o1;
  out1b[(long long)row * DD + t] = __float2bfloat16(o0);
  out1b[(long long)row * DD + t + 256] = __float2bfloat16(o1);
}

// ---------------- residual + LN2 -> out (wave-shuffle reduce) ----------------
__global__ __launch_bounds__(256)
void ln2_kernel(const float* __restrict__ a, const float* __restrict__ b2,
                const float* __restrict__ g, const float* __restrict__ bta,
                float* __restrict__ out)
{
  const int row = blockIdx.x;
  const int t = threadIdx.x;
  const int lane = t & 63, wave = t >> 6;
  __shared__ float red[8];
  float v0 = a[(long long)row * DD + t]       + b2[(long long)row * DD + t];
  float v1 = a[(long long)row * DD + t + 256] + b2[(long long)row * DD + t + 256];
  float s = v0 + v1;
#pragma unroll
  for (int o = 32; o > 0; o >>= 1) s += __shfl_xor(s, o);
  if (lane == 0) red[wave] = s;
  __syncthreads();
  float mu = (red[0] + red[1] + red[2] + red[3]) * (1.f / 512.f);
  float d0 = v0 - mu, d1 = v1 - mu;
  float vs = d0 * d0 + d1 * d1;
#pragma unroll
  for (int o = 32; o > 0; o >>= 1) vs += __shfl_xor(vs, o);
  if (lane == 0) red[4 + wave] = vs;
  __syncthreads();
  float inv = 1.f / sqrtf((red[4] + red[5] + red[6] + red[7]) * (1.f / 512.f) + 1e-6f);
  out[(long long)row * DD + t]       = d0 * inv * g[t]       + bta[t];
  out[(long long)row * DD + t + 256] = d1 * inv * g[t + 256] + bta[t + 256];
}

extern "C" void kernel_launch(void* const* d_in, const int* in_sizes, int n_in,
                              void* d_out, int out_size, void* d_ws, size_t ws_size,
                              hipStream_t stream) {
  const float* x      = (const float*)d_in[0];
  const float* adjoin = (const float*)d_in[1];
  const float* dist   = (const float*)d_in[2];
  const float* wq1=(const float*)d_in[3],  *bq1=(const float*)d_in[4];
  const float* wk1=(const float*)d_in[5],  *bk1=(const float*)d_in[6];
  const float* wv1=(const float*)d_in[7],  *bv1=(const float*)d_in[8];
  const float* wo1=(const float*)d_in[9],  *bo1=(const float*)d_in[10];
  const float* wq2=(const float*)d_in[11], *bq2=(const float*)d_in[12];
  const float* wk2=(const float*)d_in[13], *bk2=(const float*)d_in[14];
  const float* wv2=(const float*)d_in[15], *bv2=(const float*)d_in[16];
  const float* wo2=(const float*)d_in[17], *bo2=(const float*)d_in[18];
  const float* vnet_w=(const float*)d_in[19], *vnet_b=(const float*)d_in[20];
  const float* qnet_w=(const float*)d_in[21], *qnet_b=(const float*)d_in[22];
  const float* h_mat=(const float*)d_in[23], *h_bias=(const float*)d_in[24];
  const float* bn_g=(const float*)d_in[25], *bn_b=(const float*)d_in[26];
  const float* bn_m=(const float*)d_in[27], *bn_v=(const float*)d_in[28];
  const float* ln1_g=(const float*)d_in[29], *ln1_b=(const float*)d_in[30];
  const float* ln2_g=(const float*)d_in[31], *ln2_b=(const float*)d_in[32];
  const float* ffn_w1=(const float*)d_in[33], *ffn_b1=(const float*)d_in[34];
  const float* ffn_w2=(const float*)d_in[35], *ffn_b2=(const float*)d_in[36];
  const int* mask = (const int*)d_in[37];

  // ---- workspace layout (bytes). Adjacent pairs relied upon for z-batched gemms.
  char* base = (char*)d_ws;
  size_t off = 0;
  auto alloc = [&](size_t bytes) { char* p = base + off; off += (bytes + 255) & ~(size_t)255; return p; };
  bf16*  xb    = (bf16*) alloc(4096LL*512*2);
  bf16*  WB1   = (bf16*) alloc(768*256*2);   // pair: WB2 follows
  bf16*  WB2   = (bf16*) alloc(768*256*2);
  float* BB1v  = (float*)alloc(768*4);       // pair: BB2v follows
  float* BB2v  = (float*)alloc(768*4);
  float* BOv   = (float*)alloc(512*4);       // [bo1|bo2]
  float* VQb   = (float*)alloc(1024*4);      // [vnet_b|qnet_b]
  float* HSv   = (float*)alloc(512*4);       // hmat[0,:]+hmat[1,:]
  bf16*  woT1  = (bf16*) alloc(256*256*2);   // pair: woT2 follows
  bf16*  woT2  = (bf16*) alloc(256*256*2);
  bf16*  vnetT = (bf16*) alloc(512*256*2);   // pair: qnetT follows
  bf16*  qnetT = (bf16*) alloc(512*256*2);
  bf16*  f1T   = (bf16*) alloc(2048*512*2);
  bf16*  f2T   = (bf16*) alloc(512*2048*2);
  bf16*  QKF   = (bf16*) alloc(16LL*8*2*512*32*2); // 8 MB packed Q|K fragments
  bf16*  VTb   = (bf16*) alloc(2LL*8*8*512*32*2);  // 4 MB blocked-transposed V
  _Float16* EP = (_Float16*)alloc(8388608);        // 8.4 MB lane-ordered extra bias (fp16)
  bf16*  CTX   = (bf16*) alloc(4096LL*256*2); // pair: CTX2 follows
  bf16*  CTX2  = (bf16*) alloc(4096LL*256*2);
  float* XL    = (float*)alloc(4096LL*256*4); // pair: XG follows
  float* XG    = (float*)alloc(4096LL*256*4);
  bf16*  XLb   = (bf16*) alloc(4096LL*256*2); // pair: XGb follows
  bf16*  XGb   = (bf16*) alloc(4096LL*256*2);
  bf16*  Vn    = (bf16*) alloc(4096LL*512*2); // pair: Qn follows
  bf16*  Qn    = (bf16*) alloc(4096LL*512*2);
  bf16*  QnT   = (bf16*) alloc(4096LL*512*2);
  bf16*  VH    = (bf16*) alloc(4096LL*512*2);
  bf16*  G     = (bf16*) alloc(8LL*512*512*2);
  float* T     = (float*)alloc(4096LL*512*4);
  float* OUT1  = (float*)alloc(4096LL*512*4);
  bf16*  OUT1b = (bf16*) alloc(4096LL*512*2);
  bf16*  H     = (bf16*) alloc(4096LL*2048*2);
  float* FFNO  = (float*)alloc(4096LL*512*4);

  float* out2 = (float*)d_out;
  float* awl  = out2 + 2097152LL;
  float* awg  = awl + 16777216LL;

  const int MR = BB * SS; // 4096
  const long long GST = (long long)SS * SS;

  // ---- pack everything to bf16 + eprep (merged, one launch) ----
  pack_all<<<dim3(4365), 256, 0, stream>>>(
      wq1, wk1, wv1, wq2, wk2, wv2, wo1, wo2, vnet_w, qnet_w, ffn_w1, ffn_w2,
      bq1, bk1, bv1, bq2, bk2, bv2, bo1, bo2, vnet_b, qnet_b, h_mat, x,
      adjoin, dist, mask,
      WB1, WB2, woT1, woT2, vnetT, qnetT, f1T, f2T, BB1v, BB2v, BOv, VQb, HSv,
      xb, EP);

  // ---- QKV projections, both branches batched; epilogue writes packed QKF + VT ----
  gemm2<128,128,0,1,0,1><<<dim3(6, 32, 2), 256, 0, stream>>>(
      xb, WB1, BB1v, nullptr, VTb, 256, 512, 256, 768,
      256LL, 768LL*256, 0LL, 768, QKF, nullptr, nullptr);

  // ---- attention, both branches, one pass ----
  attn_fused<<<dim3(8, NH, 16), 256, 0, stream>>>(
      QKF, VTb, mask, EP, awl, awg, CTX, CTX2);

  // ---- output projections, batched over z ----
  gemm2<64,64,3,1,0,0><<<dim3(4, 64, 2), 256, 0, stream>>>(
      CTX, woT1, BOv, XL, XLb, 256, 256, 256, 256,
      4096LL*256, 256LL*256, 4096LL*256, 256, nullptr, nullptr, nullptr);

  // ---- BAN v_/q_ nets batched; z==0 also emits VH=v_*hsum; z==1 also emits QnT ----
  gemm2<64,64,2,1,1,2><<<dim3(8, 64, 2), 256, 0, stream>>>(
      XLb, vnetT, VQb, nullptr, Vn, 256, 256, 256, 512,
      4096LL*256, 512LL*256, 4096LL*512, 512, VH, HSv, QnT);

  gemm2<64,64,2,2,0,0><<<dim3(8, 8, BB), 256, 0, stream>>>(
      VH, Qn, h_bias, nullptr, G, 512, 512, 512, 512, GST, GST, GST, 0, nullptr, nullptr, nullptr);
  gemm2<64,64,1,0,0,0><<<dim3(8, 8, BB), 256, 0, stream>>>(
      G, QnT, nullptr, T, nullptr, 512, 512, 512, 512, GST, GST, GST, 0, nullptr, nullptr, nullptr);

  // ---- BN + gate + residual + LN1 ----
  bn_gate_ln1_kernel<<<dim3(MR), 256, 0, stream>>>(
      x, Vn, T, XL, XG, bn_g, bn_b, bn_m, bn_v, ln1_g, ln1_b, OUT1, OUT1b);

  // ---- FFN ----
  gemm2<128,128,2,1,2,0><<<dim3(16, 32, 1), 256, 0, stream>>>(
      OUT1b, f1T, ffn_b1, nullptr, H, 512, 512, 512, 2048, 0, 0, 0, 0, nullptr, nullptr, nullptr);
  gemm2<64,64,1,1,0,0><<<dim3(8, 64, 1), 256, 0, stream>>>(
      H, f2T, ffn_b2, FFNO, nullptr, 2048, 2048, 2048, 512, 0, 0, 0, 0, nullptr, nullptr, nullptr);

  // ---- residual + LN2 -> out ----
  ln2_kernel<<<dim3(MR), 256, 0, stream>>>(OUT1, FFNO, ln2_g, ln2_b, out2);
}

// Round 11
// 432.802 us; speedup vs baseline: 1.1347x; 1.0258x over previous
//
#include <hip/hip_runtime.h>
#include <hip/hip_bf16.h>

typedef __hip_bfloat16 bf16;
typedef __attribute__((ext_vector_type(8))) short bf16x8;
typedef __attribute__((ext_vector_type(4))) float f32x4;
typedef __attribute__((ext_vector_type(4))) _Float16 f16x4;
typedef unsigned int u32;

#define BB 8
#define SS 512
#define DD 512
#define NH 8
#define DHm 256
#define DFF 2048

__device__ __forceinline__ void gl_lds16(const void* g, void* l) {
  __builtin_amdgcn_global_load_lds((const __attribute__((address_space(1))) void*)g,
                                   (__attribute__((address_space(3))) void*)l, 16, 0, 0);
}

__device__ __forceinline__ bf16x8 cvt8(const float* p) {
  union { bf16x8 v; bf16 h[8]; } u;
  float4 f0 = *(const float4*)p, f1 = *(const float4*)(p + 4);
  u.h[0]=__float2bfloat16(f0.x); u.h[1]=__float2bfloat16(f0.y);
  u.h[2]=__float2bfloat16(f0.z); u.h[3]=__float2bfloat16(f0.w);
  u.h[4]=__float2bfloat16(f1.x); u.h[5]=__float2bfloat16(f1.y);
  u.h[6]=__float2bfloat16(f1.z); u.h[7]=__float2bfloat16(f1.w);
  return u.v;
}

// ================= bf16 MFMA GEMM, double-buffered BK=32 2-phase K-loop =================
// (r8 structure — measured best. r9's BK=64 cut blocks/CU; occupancy/TLP was the
// critical resource, not barrier count. Reverted and kept.)
// A (M,K) bf16 row-major; B (N,K) bf16 row-major (pre-transposed weights).
// STAGE(next buf) issued BEFORE compute(cur buf); one vmcnt(0)+s_barrier per K-iter.
// SMODE: 1=fp32, 2=bf16, 3=both, 0=none. BIASM: 0 none, 1 per-col (+z*sBias), 2 scalar bias[0]+bias[1].
// VTM: 0 none; 1 QKV packed (QKF via Cb2, VT via Cb); 2 = z==0: Cb2[ci]=v*cscale[col],
//      z==1: emit transposed tile to Cb3 (QnT) via dedicated LDS scratch (coalesced).
#define STAGE_G(buf, k0)                                                   \
  {                                                                        \
    _Pragma("unroll")                                                      \
    for (int j = 0; j < BM / 64; j++)                                      \
      gl_lds16(Ab + (long long)(srow + j * 64) * lda + (k0) + skc,         \
               (char*)As[buf] + wave * 1024 + j * 4096);                   \
    _Pragma("unroll")                                                      \
    for (int j = 0; j < BN / 64; j++)                                      \
      gl_lds16(Bb + (long long)(srow + j * 64) * ldb + (k0) + skc,         \
               (char*)Bs[buf] + wave * 1024 + j * 4096);                   \
  }

template<int BM, int BN, int SMODE, int BIASM, int ACT, int VTM>
__global__ __launch_bounds__(256)
void gemm2(const bf16* __restrict__ A, const bf16* __restrict__ B,
           const float* __restrict__ bias, float* __restrict__ Cf,
           bf16* __restrict__ Cb, int K, int lda, int ldb, int ldc,
           long long sA, long long sB, long long sC, int sBias,
           bf16* __restrict__ Cb2, const float* __restrict__ cscale,
           bf16* __restrict__ Cb3)
{
  __shared__ bf16 As[2][BM * 32];
  __shared__ bf16 Bs[2][BN * 32];
  __shared__ bf16 tls[(VTM == 2) ? 64 * 65 : 1];   // transpose scratch (vnet only)
  const int t = threadIdx.x, lane = t & 63, wave = t >> 6;
  const int l15 = lane & 15, quad = lane >> 4;
  constexpr int WMT = BM / 32, WNT = BN / 32;    // 16-tiles per wave in m/n
  const int wm = (wave & 1) * (BM / 2), wn = (wave >> 1) * (BN / 2);
  const int row0 = blockIdx.y * BM, col0 = blockIdx.x * BN;
  const bf16* Ab = A + (long long)blockIdx.z * sA + (long long)row0 * lda;
  const bf16* Bb = B + (long long)blockIdx.z * sB + (long long)col0 * ldb;
  const int srow = wave * 16 + (lane >> 2), skc = (lane & 3) << 3;

  f32x4 acc[WMT][WNT] = {};

  STAGE_G(0, 0)
  asm volatile("s_waitcnt vmcnt(0)" ::: "memory");
  __builtin_amdgcn_s_barrier();

  int cur = 0;
  for (int k0 = 0; k0 < K; k0 += 32) {
    if (k0 + 32 < K) STAGE_G(cur ^ 1, k0 + 32)
    bf16x8 af[WMT], bfr[WNT];
#pragma unroll
    for (int i = 0; i < WMT; i++) af[i]  = *(const bf16x8*)&As[cur][(wm + i * 16 + l15) * 32 + quad * 8];
#pragma unroll
    for (int j = 0; j < WNT; j++) bfr[j] = *(const bf16x8*)&Bs[cur][(wn + j * 16 + l15) * 32 + quad * 8];
#pragma unroll
    for (int i = 0; i < WMT; i++)
#pragma unroll
      for (int j = 0; j < WNT; j++)
        acc[i][j] = __builtin_amdgcn_mfma_f32_16x16x32_bf16(af[i], bfr[j], acc[i][j], 0, 0, 0);
    // staged loads (issued at loop top) had the whole compute phase to land
    asm volatile("s_waitcnt vmcnt(0)" ::: "memory");
    __builtin_amdgcn_s_barrier();
    cur ^= 1;
  }

  float sb = 0.f;
  if (BIASM == 2) sb = bias[0] + bias[1];
  bf16 (*tl)[65] = (bf16(*)[65])tls;
#pragma unroll
  for (int i = 0; i < WMT; i++)
#pragma unroll
    for (int j = 0; j < WNT; j++) {
      int col = col0 + wn + j * 16 + l15;
      float bv = (BIASM == 1) ? bias[(long long)blockIdx.z * sBias + col] : sb;
      float vv[4];
#pragma unroll
      for (int r = 0; r < 4; r++) {
        float v = acc[i][j][r] + bv;
        if (ACT == 1) v = fmaxf(v, 0.f);
        if (ACT == 2) v = 0.5f * v * (1.f + erff(v * 0.70710678118654752f));
        vv[r] = v;
      }
      const int rowb = row0 + wm + i * 16 + (quad << 2);
      if (VTM == 1) {
        const int bidx = rowb >> 9, kpos = rowb & 511;
        const long long zz8 = (long long)blockIdx.z * 8 + bidx;
        if (col < 512) {
          // QKF packed: [zz8][h][part(0=Q,1=K)][kpos][dep32]
          const int part = col >> 8, hh = (col >> 5) & 7, dep = col & 31;
          bf16* dst = Cb2 + (((zz8 * 8 + hh) * 2 + part) * 512 + (long long)kpos) * 32 + dep;
#pragma unroll
          for (int r = 0; r < 4; r++) dst[r * 32] = __float2bfloat16(vv[r]);
        } else {
          // VT packed: [zz8][h][kpos>>3][dep][kpos&7]
          const int hh = (col - 512) >> 5, dep = (col - 512) & 31;
          long long vo = ((zz8 * 8 + hh) * 64 + (kpos >> 3)) * 32 + dep;
          bf16 h0 = __float2bfloat16(vv[0]), h1 = __float2bfloat16(vv[1]);
          bf16 h2 = __float2bfloat16(vv[2]), h3 = __float2bfloat16(vv[3]);
          short4 pk;
          pk.x = *(short*)&h0; pk.y = *(short*)&h1; pk.z = *(short*)&h2; pk.w = *(short*)&h3;
          *(short4*)(Cb + vo * 8 + (kpos & 7)) = pk;
        }
      } else {
#pragma unroll
        for (int r = 0; r < 4; r++) {
          long long ci = (long long)blockIdx.z * sC + (long long)(rowb + r) * ldc + col;
          bf16 hb = __float2bfloat16(vv[r]);
          if (SMODE & 1) Cf[ci] = vv[r];
          if (SMODE & 2) Cb[ci] = hb;
          if (VTM == 2) {
            if (blockIdx.z == 0) Cb2[ci] = __float2bfloat16(vv[r] * cscale[col]);
            else tl[wm + i * 16 + (quad << 2) + r][wn + j * 16 + l15] = hb;
          }
        }
      }
    }

  // ---- VTM==2, z==1: emit transposed tile (QnT[c][r] = Qn[r][c]) coalesced ----
  if (VTM == 2 && blockIdx.z == 1) {
    __syncthreads();
    const int o_r = t >> 2;                 // output row within tile = original col
    const int jb = (t & 3) * 16;            // 16 source rows handled by this thread
    const int bidx = row0 >> 9;             // batch (tiles never cross 512-row bound)
    bf16* dst = Cb3 + (long long)bidx * 262144 + (long long)(col0 + o_r) * 512 + (row0 & 511) + jb;
    union { bf16x8 v; bf16 h[8]; } u0, u1;
#pragma unroll
    for (int j = 0; j < 8; j++) { u0.h[j] = tl[jb + j][o_r]; u1.h[j] = tl[jb + 8 + j][o_r]; }
    *(bf16x8*)dst = u0.v;
    *(bf16x8*)(dst + 8) = u1.v;
  }
}

// ================= fused MFMA attention, one pass =================
// XCD-aware 1D grid (1024 blocks): id&7 selects a zz-PAIR group. Assuming
// round-robin id%8 -> XCD, each XCD's 128 blocks share {QKF,VT,EP} for just
// 2 zz values (~2.5 MB) -> L2-resident, killing the 8x cross-XCD QKF re-fetch
// (r10: FETCH 62 MB vs 21 MB unique). Within a group h varies slowest so
// consecutive blocks share the same QKF slice in time. Bijective remap only —
// wrong XCD-assignment assumption costs locality, never correctness.
__global__ __launch_bounds__(256, 2)
void attn_fused(const bf16* __restrict__ QKF, const bf16* __restrict__ VT,
                const int* __restrict__ mask, const _Float16* __restrict__ EP,
                float* __restrict__ awl, float* __restrict__ awg,
                bf16* __restrict__ ctx1, bf16* __restrict__ ctx2)
{
  const int id = blockIdx.x;
  const int g = id & 7, inner = id >> 3;
  const int zz = g * 2 + (inner & 1);
  const int qt = (inner >> 1) & 7;
  const int h = (inner >> 4) & 7;
  const int b = zz & 7, branch = zz >> 3;
  float* __restrict__ aw = branch ? awg : awl;
  bf16* __restrict__ ctx = branch ? ctx2 : ctx1;

  const int t = threadIdx.x, lane = t & 63, wave = t >> 6;
  const int l15 = lane & 15, quad = lane >> 4;
  __shared__ bf16x8 Vt[64][32];                 // 32 KB
  alignas(16) __shared__ bf16 Pl[4][2048];      // 16 KB per-wave swizzled e chunk
  __shared__ float mvalf[512];                  // 2 KB

  // ---- stage V via async copy from pre-transposed VT ----
  const bf16* VTs = VT + ((long long)zz * 8 + h) * 16384;
#pragma unroll
  for (int j = 0; j < 8; j++)
    gl_lds16(VTs + (long long)t * 8 + j * 2048, (char*)Vt + wave * 1024 + j * 4096);

  { int2 m2 = *(const int2*)(mask + b * SS + t * 2);
    mvalf[t * 2]     = (float)m2.x * -1e9f;
    mvalf[t * 2 + 1] = (float)m2.y * -1e9f; }

  const int q0 = qt * 64 + wave * 16;
  const bf16* Qbase = QKF + ((long long)zz * 8 + h) * 2 * 16384;
  const bf16* Kbase = Qbase + 16384;
  bf16x8 qfrag = *(const bf16x8*)(Qbase + (long long)(q0 + l15) * 32 + quad * 8);
  __syncthreads();

  const float scale_inv = 0.17677669529663688f;
  const f16x4* Ep = (const f16x4*)EP + (((long long)zz * 8 + qt) * 4 + wave) * 2048;

  u32 eh[64];
  float rsum[4] = {0.f, 0.f, 0.f, 0.f};
  f32x4 oacc[2] = {};
  short* Pw = (short*)Pl[wave];
  const int rkey = ((l15 >> 2) ^ l15) & 3;

#pragma unroll
  for (int c = 0; c < 4; c++) {
#pragma unroll
    for (int kcl = 0; kcl < 8; kcl++) {
      const int kc = c * 8 + kcl;
      const int kpos = kc * 16 + l15;
      bf16x8 kfrag = *(const bf16x8*)(Kbase + (long long)kpos * 32 + quad * 8);
      f16x4 e4 = Ep[kc * 64 + lane];
      f32x4 a = __builtin_amdgcn_mfma_f32_16x16x32_bf16(qfrag, kfrag, f32x4{0.f,0.f,0.f,0.f}, 0, 0, 0);
      float mv = (branch == 0) ? 0.f : mvalf[kpos];
      u32 p01 = 0, p23 = 0;
#pragma unroll
      for (int r = 0; r < 4; r++) {
        float s = (branch == 0) ? fmaf(a[r], scale_inv, (float)e4[r])
                                : fmaf(fmaxf(a[r], 0.f), (float)e4[r], mv);
        float e = __expf(s);
        rsum[r] += e;
        u32 xb = __float_as_uint(e);
        u32 b16 = (xb + 0x7FFFu + ((xb >> 16) & 1u)) >> 16;   // RNE bf16, int-only
        if (r == 0)      p01 = b16;
        else if (r == 1) p01 |= b16 << 16;
        else if (r == 2) p23 = b16;
        else             p23 |= b16 << 16;
        const int key = (quad ^ r) & 3;          // ((row>>2)^row)&3 for row=quad*4+r
        const int off = (quad * 4 + r) * 256 + (((kcl * 16 + l15) * 2) ^ (key << 5));
        *(short*)((char*)Pw + off) = (short)b16;
      }
      eh[kc * 2]     = p01;
      eh[kc * 2 + 1] = p23;
    }
    // ---- PV on this chunk (unnormalized e) ----
    __builtin_amdgcn_s_setprio(1);
#pragma unroll
    for (int k2 = 0; k2 < 4; k2++) {
      const int off = l15 * 256 + ((k2 * 64 + quad * 16) ^ (rkey << 5));
      bf16x8 afr = *(const bf16x8*)((const char*)Pw + off);
      const int blk = (c * 4 + k2) * 4 + quad;
      oacc[0] = __builtin_amdgcn_mfma_f32_16x16x32_bf16(afr, Vt[blk][l15],      oacc[0], 0, 0, 0);
      oacc[1] = __builtin_amdgcn_mfma_f32_16x16x32_bf16(afr, Vt[blk][16 + l15], oacc[1], 0, 0, 0);
    }
    __builtin_amdgcn_s_setprio(0);
  }

  // ---- row sums -> 1/sum ----
  float rsi[4];
#pragma unroll
  for (int r = 0; r < 4; r++) {
    float v = rsum[r];
    v += __shfl_xor(v, 1, 16);
    v += __shfl_xor(v, 2, 16);
    v += __shfl_xor(v, 4, 16);
    v += __shfl_xor(v, 8, 16);
    rsi[r] = 1.f / v;
  }

  // ---- ctx = (e.V) * rsi ----
#pragma unroll
  for (int n = 0; n < 2; n++)
#pragma unroll
    for (int r = 0; r < 4; r++) {
      int q = q0 + quad * 4 + r;
      ctx[(long long)(b * SS + q) * DHm + h * 32 + n * 16 + l15] =
          __float2bfloat16(oacc[n][r] * rsi[r]);
    }

  // ---- aw = unpack(e) * rsi (plain cached stores) ----
  float* awp = aw + (((long long)(b * NH + h) * SS + q0)) * SS;
#pragma unroll
  for (int kc = 0; kc < 32; kc++) {
    u32 p01 = eh[kc * 2], p23 = eh[kc * 2 + 1];
#pragma unroll
    for (int r = 0; r < 4; r++) {
      u32 bits = (r == 0) ? (p01 & 0xFFFFu) : (r == 1) ? (p01 >> 16)
               : (r == 2) ? (p23 & 0xFFFFu) : (p23 >> 16);
      float e = __uint_as_float(bits << 16);
      awp[(long long)(quad * 4 + r) * SS + kc * 16 + l15] = e * rsi[r];
    }
  }
}

// ================= pack_all + eprep merged =================
__device__ __forceinline__ void tr_tile(const float* __restrict__ src, bf16* __restrict__ dst,
                                        int K, int N, int tile) {
  __shared__ float tl[32][33];
  int tilesN = N >> 5;
  int tk = tile / tilesN, tn = tile % tilesN;
  int c = threadIdx.x & 31, r0 = threadIdx.x >> 5;
#pragma unroll
  for (int i = 0; i < 4; i++) {
    int r = r0 + i * 8;
    tl[r][c] = src[(long long)(tk * 32 + r) * N + tn * 32 + c];
  }
  __syncthreads();
#pragma unroll
  for (int i = 0; i < 4; i++) {
    int r = r0 + i * 8;
    dst[(long long)(tn * 32 + r) * K + tk * 32 + c] = __float2bfloat16(tl[c][r]);
  }
}

__global__ __launch_bounds__(256)
void pack_all(const float* wq1, const float* wk1, const float* wv1,
              const float* wq2, const float* wk2, const float* wv2,
              const float* wo1, const float* wo2,
              const float* vnet_w, const float* qnet_w,
              const float* ffn_w1, const float* ffn_w2,
              const float* bq1, const float* bk1, const float* bv1,
              const float* bq2, const float* bk2, const float* bv2,
              const float* bo1, const float* bo2,
              const float* vnet_b, const float* qnet_b,
              const float* h_mat,
              const float* x,
              const float* adjoin, const float* dist, const int* mask,
              bf16* WB1, bf16* WB2, bf16* woT1, bf16* woT2,
              bf16* vnetT, bf16* qnetT, bf16* f1T, bf16* f2T,
              float* BB1v, float* BB2v, float* BOv, float* VQb, float* HSv,
              bf16* xb, _Float16* EP)
{
  int blk = blockIdx.x;
  if (blk < 64)        { tr_tile(wq1, WB1,            256, 256, blk); return; }
  if (blk < 128)       { tr_tile(wk1, WB1 + 256*256,  256, 256, blk-64); return; }
  if (blk < 192)       { tr_tile(wv1, WB1 + 512*256,  256, 256, blk-128); return; }
  if (blk < 256)       { tr_tile(wq2, WB2,            256, 256, blk-192); return; }
  if (blk < 320)       { tr_tile(wk2, WB2 + 256*256,  256, 256, blk-256); return; }
  if (blk < 384)       { tr_tile(wv2, WB2 + 512*256,  256, 256, blk-320); return; }
  if (blk < 448)       { tr_tile(wo1, woT1,           256, 256, blk-384); return; }
  if (blk < 512)       { tr_tile(wo2, woT2,           256, 256, blk-448); return; }
  if (blk < 640)       { tr_tile(vnet_w, vnetT,       256, 512, blk-512); return; }
  if (blk < 768)       { tr_tile(qnet_w, qnetT,       256, 512, blk-640); return; }
  if (blk < 1792)      { tr_tile(ffn_w1, f1T,         512, 2048, blk-768); return; }
  if (blk < 2816)      { tr_tile(ffn_w2, f2T,         2048, 512, blk-1792); return; }
  if (blk < 3840) {
    long long i0 = (long long)(blk - 2816) * 2048 + threadIdx.x * 8;
    *(bf16x8*)(xb + i0) = cvt8(x + i0);
    return;
  }
  if (blk < 3846) {
    int b = blk - 3840; // 0..5
    const float* src = b==0?bq1 : b==1?bk1 : b==2?bv1 : b==3?bq2 : b==4?bk2 : bv2;
    float* dst = (b < 3 ? BB1v : BB2v) + (b % 3) * 256;
    dst[threadIdx.x] = src[threadIdx.x];
    return;
  }
  if (blk < 3848) {
    int b = blk - 3846; // 0..1
    BOv[b * 256 + threadIdx.x] = (b ? bo2 : bo1)[threadIdx.x];
    return;
  }
  if (blk < 3852) {
    int b = blk - 3848; // 0..3: [vnet_b lo, vnet_b hi, qnet_b lo, qnet_b hi]
    const float* src = (b < 2) ? vnet_b : qnet_b;
    VQb[b * 256 + threadIdx.x] = src[(b & 1) * 256 + threadIdx.x];
    return;
  }
  if (blk < 3853) {
    int t = threadIdx.x;
    HSv[t]       = h_mat[t]       + h_mat[512 + t];
    HSv[t + 256] = h_mat[256 + t] + h_mat[768 + t];
    return;
  }
  // ---- eprep blocks: reorder extra-bias into MFMA lane order (fp16) ----
  {
    const int e = blk - 3853;             // 0..511
    const int qt = e & 7, kt = (e >> 3) & 3, zz = e >> 5;
    const int b = zz & 7, branch = zz >> 3;
    const float* E = (branch ? dist : adjoin) + ((long long)b * SS + qt * 64) * SS + kt * 128;
    __shared__ float tile[64][129];
    const int t = threadIdx.x;
    const int r0 = t >> 5, c4 = (t & 31) * 4;
#pragma unroll
    for (int jj = 0; jj < 8; jj++) {
      int row = r0 + jj * 8;
      float4 f = *(const float4*)(E + (long long)row * SS + c4);
      tile[row][c4 + 0] = f.x; tile[row][c4 + 1] = f.y;
      tile[row][c4 + 2] = f.z; tile[row][c4 + 3] = f.w;
    }
    __syncthreads();
    const int lane = t & 63, wq = t >> 6, l15 = lane & 15, quad = lane >> 4;
    const float scale_inv = 0.17677669529663688f; // 1/sqrt(32)
    f16x4* out = (f16x4*)EP;
#pragma unroll
    for (int kcl = 0; kcl < 8; kcl++) {
      int kk = kcl * 16 + l15;
      f16x4 o;
      if (branch == 0) {
        float mv = (float)mask[b * SS + kt * 128 + kk] * -1e9f;
#pragma unroll
        for (int r = 0; r < 4; r++)
          o[r] = (_Float16)(tile[wq * 16 + quad * 4 + r][kk] + mv);
      } else {
#pragma unroll
        for (int r = 0; r < 4; r++) {
          float ev = tile[wq * 16 + quad * 4 + r][kk];
          o[r] = (_Float16)(3.7182818284590452f / (1.f + __expf(1.f - ev)) * scale_inv);
        }
      }
      out[((((long long)zz * 8 + qt) * 4 + wq) * 32 + (kt * 8 + kcl)) * 64 + lane] = o;
    }
  }
}

// ---------------- BN(eval) + gate + residual + LN1 (dual-store, wave-shuffle reduce) ----------------
__global__ __launch_bounds__(256)
void bn_gate_ln1_kernel(const float* __restrict__ x, const bf16* __restrict__ vbuf,
                        const float* __restrict__ T, const float* __restrict__ xl,
                        const float* __restrict__ xg,
                        const float* __restrict__ bng, const float* __restrict__ bnb,
                        const float* __restrict__ bnm, const float* __restrict__ bnv,
                        const float* __restrict__ lng, const float* __restrict__ lnb,
                        float* __restrict__ out1, bf16* __restrict__ out1b)
{
  const int row = blockIdx.x;
  const int t = threadIdx.x;
  const int lane = t & 63, wave = t >> 6;
  __shared__ float red[8];
  float val[2];
#pragma unroll
  for (int i = 0; i < 2; i++) {
    int c = t + i * 256;
    long long idx = (long long)row * DD + c;
    float lg = __bfloat162float(vbuf[idx]) * T[idx];
    float bn = (lg - bnm[c]) / sqrtf(bnv[c] + 1e-3f) * bng[c] + bnb[c];
    float gate = (c < DHm) ? xl[(long long)row * DHm + c] : xg[(long long)row * DHm + (c - DHm)];
    val[i] = x[idx] + bn * gate;
  }
  float s = val[0] + val[1];
#pragma unroll
  for (int o = 32; o > 0; o >>= 1) s += __shfl_xor(s, o);
  if (lane == 0) red[wave] = s;
  __syncthreads();
  float mu = (red[0] + red[1] + red[2] + red[3]) * (1.f / 512.f);
  float d0 = val[0] - mu, d1 = val[1] - mu;
  float vs = d0 * d0 + d1 * d1;
#pragma unroll
  for (int o = 32; o > 0; o >>= 1) vs += __shfl_xor(vs, o);
  if (lane == 0) red[4 + wave] = vs;
  __syncthreads();
  float inv = 1.f / sqrtf((red[4] + red[5] + red[6] + red[7]) * (1.f / 512.f) + 1e-6f);
  float o0 = d0 * inv * lng[t] + lnb[t];
  float o1 = d1 * inv * lng[t + 256] + lnb[t + 256];
  out1[(long long)row * DD + t] = o0;
  out1[(long long)row * DD + t + 256] = o1;
  out1b[(long long)row * DD + t] = __float2bfloat16(o0);
  out1b[(long long)row * DD + t + 256] = __float2bfloat16(o1);
}

// ---------------- residual + LN2 -> out (wave-shuffle reduce) ----------------
__global__ __launch_bounds__(256)
void ln2_kernel(const float* __restrict__ a, const float* __restrict__ b2,
                const float* __restrict__ g, const float* __restrict__ bta,
                float* __restrict__ out)
{
  const int row = blockIdx.x;
  const int t = threadIdx.x;
  const int lane = t & 63, wave = t >> 6;
  __shared__ float red[8];
  float v0 = a[(long long)row * DD + t]       + b2[(long long)row * DD + t];
  float v1 = a[(long long)row * DD + t + 256] + b2[(long long)row * DD + t + 256];
  float s = v0 + v1;
#pragma unroll
  for (int o = 32; o > 0; o >>= 1) s += __shfl_xor(s, o);
  if (lane == 0) red[wave] = s;
  __syncthreads();
  float mu = (red[0] + red[1] + red[2] + red[3]) * (1.f / 512.f);
  float d0 = v0 - mu, d1 = v1 - mu;
  float vs = d0 * d0 + d1 * d1;
#pragma unroll
  for (int o = 32; o > 0; o >>= 1) vs += __shfl_xor(vs, o);
  if (lane == 0) red[4 + wave] = vs;
  __syncthreads();
  float inv = 1.f / sqrtf((red[4] + red[5] + red[6] + red[7]) * (1.f / 512.f) + 1e-6f);
  out[(long long)row * DD + t]       = d0 * inv * g[t]       + bta[t];
  out[(long long)row * DD + t + 256] = d1 * inv * g[t + 256] + bta[t + 256];
}

extern "C" void kernel_launch(void* const* d_in, const int* in_sizes, int n_in,
                              void* d_out, int out_size, void* d_ws, size_t ws_size,
                              hipStream_t stream) {
  const float* x      = (const float*)d_in[0];
  const float* adjoin = (const float*)d_in[1];
  const float* dist   = (const float*)d_in[2];
  const float* wq1=(const float*)d_in[3],  *bq1=(const float*)d_in[4];
  const float* wk1=(const float*)d_in[5],  *bk1=(const float*)d_in[6];
  const float* wv1=(const float*)d_in[7],  *bv1=(const float*)d_in[8];
  const float* wo1=(const float*)d_in[9],  *bo1=(const float*)d_in[10];
  const float* wq2=(const float*)d_in[11], *bq2=(const float*)d_in[12];
  const float* wk2=(const float*)d_in[13], *bk2=(const float*)d_in[14];
  const float* wv2=(const float*)d_in[15], *bv2=(const float*)d_in[16];
  const float* wo2=(const float*)d_in[17], *bo2=(const float*)d_in[18];
  const float* vnet_w=(const float*)d_in[19], *vnet_b=(const float*)d_in[20];
  const float* qnet_w=(const float*)d_in[21], *qnet_b=(const float*)d_in[22];
  const float* h_mat=(const float*)d_in[23], *h_bias=(const float*)d_in[24];
  const float* bn_g=(const float*)d_in[25], *bn_b=(const float*)d_in[26];
  const float* bn_m=(const float*)d_in[27], *bn_v=(const float*)d_in[28];
  const float* ln1_g=(const float*)d_in[29], *ln1_b=(const float*)d_in[30];
  const float* ln2_g=(const float*)d_in[31], *ln2_b=(const float*)d_in[32];
  const float* ffn_w1=(const float*)d_in[33], *ffn_b1=(const float*)d_in[34];
  const float* ffn_w2=(const float*)d_in[35], *ffn_b2=(const float*)d_in[36];
  const int* mask = (const int*)d_in[37];

  // ---- workspace layout (bytes). Adjacent pairs relied upon for z-batched gemms.
  char* base = (char*)d_ws;
  size_t off = 0;
  auto alloc = [&](size_t bytes) { char* p = base + off; off += (bytes + 255) & ~(size_t)255; return p; };
  bf16*  xb    = (bf16*) alloc(4096LL*512*2);
  bf16*  WB1   = (bf16*) alloc(768*256*2);   // pair: WB2 follows
  bf16*  WB2   = (bf16*) alloc(768*256*2);
  float* BB1v  = (float*)alloc(768*4);       // pair: BB2v follows
  float* BB2v  = (float*)alloc(768*4);
  float* BOv   = (float*)alloc(512*4);       // [bo1|bo2]
  float* VQb   = (float*)alloc(1024*4);      // [vnet_b|qnet_b]
  float* HSv   = (float*)alloc(512*4);       // hmat[0,:]+hmat[1,:]
  bf16*  woT1  = (bf16*) alloc(256*256*2);   // pair: woT2 follows
  bf16*  woT2  = (bf16*) alloc(256*256*2);
  bf16*  vnetT = (bf16*) alloc(512*256*2);   // pair: qnetT follows
  bf16*  qnetT = (bf16*) alloc(512*256*2);
  bf16*  f1T   = (bf16*) alloc(2048*512*2);
  bf16*  f2T   = (bf16*) alloc(512*2048*2);
  bf16*  QKF   = (bf16*) alloc(16LL*8*2*512*32*2); // 8 MB packed Q|K fragments
  bf16*  VTb   = (bf16*) alloc(2LL*8*8*512*32*2);  // 4 MB blocked-transposed V
  _Float16* EP = (_Float16*)alloc(8388608);        // 8.4 MB lane-ordered extra bias (fp16)
  bf16*  CTX   = (bf16*) alloc(4096LL*256*2); // pair: CTX2 follows
  bf16*  CTX2  = (bf16*) alloc(4096LL*256*2);
  float* XL    = (float*)alloc(4096LL*256*4); // pair: XG follows
  float* XG    = (float*)alloc(4096LL*256*4);
  bf16*  XLb   = (bf16*) alloc(4096LL*256*2); // pair: XGb follows
  bf16*  XGb   = (bf16*) alloc(4096LL*256*2);
  bf16*  Vn    = (bf16*) alloc(4096LL*512*2); // pair: Qn follows
  bf16*  Qn    = (bf16*) alloc(4096LL*512*2);
  bf16*  QnT   = (bf16*) alloc(4096LL*512*2);
  bf16*  VH    = (bf16*) alloc(4096LL*512*2);
  bf16*  G     = (bf16*) alloc(8LL*512*512*2);
  float* T     = (float*)alloc(4096LL*512*4);
  float* OUT1  = (float*)alloc(4096LL*512*4);
  bf16*  OUT1b = (bf16*) alloc(4096LL*512*2);
  bf16*  H     = (bf16*) alloc(4096LL*2048*2);
  float* FFNO  = (float*)alloc(4096LL*512*4);

  float* out2 = (float*)d_out;
  float* awl  = out2 + 2097152LL;
  float* awg  = awl + 16777216LL;

  const int MR = BB * SS; // 4096
  const long long GST = (long long)SS * SS;

  // ---- pack everything to bf16 + eprep (merged, one launch) ----
  pack_all<<<dim3(4365), 256, 0, stream>>>(
      wq1, wk1, wv1, wq2, wk2, wv2, wo1, wo2, vnet_w, qnet_w, ffn_w1, ffn_w2,
      bq1, bk1, bv1, bq2, bk2, bv2, bo1, bo2, vnet_b, qnet_b, h_mat, x,
      adjoin, dist, mask,
      WB1, WB2, woT1, woT2, vnetT, qnetT, f1T, f2T, BB1v, BB2v, BOv, VQb, HSv,
      xb, EP);

  // ---- QKV projections, both branches batched; epilogue writes packed QKF + VT ----
  gemm2<128,128,0,1,0,1><<<dim3(6, 32, 2), 256, 0, stream>>>(
      xb, WB1, BB1v, nullptr, VTb, 256, 512, 256, 768,
      256LL, 768LL*256, 0LL, 768, QKF, nullptr, nullptr);

  // ---- attention, both branches, one pass (XCD-aware 1D grid) ----
  attn_fused<<<dim3(1024), 256, 0, stream>>>(
      QKF, VTb, mask, EP, awl, awg, CTX, CTX2);

  // ---- output projections, batched over z ----
  gemm2<64,64,3,1,0,0><<<dim3(4, 64, 2), 256, 0, stream>>>(
      CTX, woT1, BOv, XL, XLb, 256, 256, 256, 256,
      4096LL*256, 256LL*256, 4096LL*256, 256, nullptr, nullptr, nullptr);

  // ---- BAN v_/q_ nets batched; z==0 also emits VH=v_*hsum; z==1 also emits QnT ----
  gemm2<64,64,2,1,1,2><<<dim3(8, 64, 2), 256, 0, stream>>>(
      XLb, vnetT, VQb, nullptr, Vn, 256, 256, 256, 512,
      4096LL*256, 512LL*256, 4096LL*512, 512, VH, HSv, QnT);

  gemm2<64,64,2,2,0,0><<<dim3(8, 8, BB), 256, 0, stream>>>(
      VH, Qn, h_bias, nullptr, G, 512, 512, 512, 512, GST, GST, GST, 0, nullptr, nullptr, nullptr);
  gemm2<64,64,1,0,0,0><<<dim3(8, 8, BB), 256, 0, stream>>>(
      G, QnT, nullptr, T, nullptr, 512, 512, 512, 512, GST, GST, GST, 0, nullptr, nullptr, nullptr);

  // ---- BN + gate + residual + LN1 ----
  bn_gate_ln1_kernel<<<dim3(MR), 256, 0, stream>>>(
      x, Vn, T, XL, XG, bn_g, bn_b, bn_m, bn_v, ln1_g, ln1_b, OUT1, OUT1b);

  // ---- FFN ----
  gemm2<128,128,2,1,2,0><<<dim3(16, 32, 1), 256, 0, stream>>>(
      OUT1b, f1T, ffn_b1, nullptr, H, 512, 512, 512, 2048, 0, 0, 0, 0, nullptr, nullptr, nullptr);
  gemm2<64,64,1,1,0,0><<<dim3(8, 64, 1), 256, 0, stream>>>(
      H, f2T, ffn_b2, FFNO, nullptr, 2048, 2048, 2048, 512, 0, 0, 0, 0, nullptr, nullptr, nullptr);

  // ---- residual + LN2 -> out ----
  ln2_kernel<<<dim3(MR), 256, 0, stream>>>(OUT1, FFNO, ln2_g, ln2_b, out2);
}